// Round 11
// baseline (439.591 us; speedup 1.0000x reference)
//
#include <hip/hip_runtime.h>
#include <hip/hip_bf16.h>

#define NEG_SLOPE 0.2f

typedef __attribute__((ext_vector_type(8))) short bf16x8;
typedef __attribute__((ext_vector_type(4))) float f32x4;

static inline int cdiv(int a, int b) { return (a + b - 1) / b; }

__device__ inline unsigned short f2bf(float x) {
  __hip_bfloat16 b = __float2bfloat16(x);
  return *reinterpret_cast<unsigned short*>(&b);
}
__device__ inline float bf2f(unsigned short u) {
  unsigned int v = (unsigned int)u << 16;
  return *reinterpret_cast<float*>(&v);
}

// ---------------- fused split+transpose (bf16 hi only) for all 3 weights ----------------
// W[K][Mo] -> T[Mo][K]; W1/W2 get k-permutation pi(k)=(k&63)*4+(k>>6)
__global__ void splitT_all(const float* __restrict__ W0, unsigned short* __restrict__ W0hi,
                           const float* __restrict__ W1, unsigned short* __restrict__ W1hi,
                           const float* __restrict__ W2, unsigned short* __restrict__ W2hi) {
  const int S0 = 256 * 256, S1 = 256 * 256, S2 = 256 * 64;
  int i = blockIdx.x * blockDim.x + threadIdx.x;
  const float* W; unsigned short* hi; int K, Mo, perm;
  if (i < S0) { W = W0; hi = W0hi; K = 256; Mo = 256; perm = 0; }
  else if (i < S0 + S1) { i -= S0; W = W1; hi = W1hi; K = 256; Mo = 256; perm = 1; }
  else if (i < S0 + S1 + S2) { i -= S0 + S1; W = W2; hi = W2hi; K = 256; Mo = 64; perm = 1; }
  else return;
  int k = i / Mo, m = i - k * Mo;
  int kk = perm ? ((k & 63) * 4 + (k >> 6)) : k;
  hi[(size_t)m * K + kk] = f2bf(W[i]);
}

// ---------------- GEMM (single bf16 MFMA) + fused attention-score partials ----------------
// CVT: stage A from f32 source. NF=4: Chi HEAD-INTERLEAVED, el/er plain store.
// NF=2: Chi standard, el/er cross-wave LDS reduce + plain store.
template <int NF, bool CVT>
__global__ __launch_bounds__(256) void gemm_split(
    const unsigned short* __restrict__ Ahi, const float* __restrict__ Af32,
    const unsigned short* __restrict__ BThi,
    unsigned short* __restrict__ Chi,
    const float* __restrict__ alv, const float* __restrict__ arv,
    float* __restrict__ el, float* __restrict__ er, int Hn, int M, int K, int Ncols) {
  constexpr int BN = NF * 32;
  __shared__ unsigned short As[128][40];
  __shared__ unsigned short Bs[BN][40];
  const int tid = threadIdx.x;
  const int row0 = blockIdx.x * 128;
  const int col0 = blockIdx.y * BN;
  const int wid = tid >> 6, lane = tid & 63;
  const int wm = wid >> 1, wn = wid & 1;
  const int l15 = lane & 15, lg = lane >> 4;
  f32x4 acc[4][NF];
#pragma unroll
  for (int m = 0; m < 4; ++m)
#pragma unroll
    for (int n = 0; n < NF; ++n) acc[m][n] = (f32x4){0.f, 0.f, 0.f, 0.f};

  const uint4 zero4 = {0u, 0u, 0u, 0u};
  for (int k0 = 0; k0 < K; k0 += 32) {
    {  // stage A
      int r = tid >> 2;
      const int kg = tid & 3;
#pragma unroll
      for (int it = 0; it < 2; ++it, r += 64) {
        const int grow = row0 + r;
        if constexpr (CVT) {
          float4 f0 = make_float4(0.f, 0.f, 0.f, 0.f), f1 = f0;
          if (grow < M) {
            f0 = *reinterpret_cast<const float4*>(&Af32[(size_t)grow * K + k0 + kg * 8]);
            f1 = *reinterpret_cast<const float4*>(&Af32[(size_t)grow * K + k0 + kg * 8 + 4]);
          }
          unsigned short t[8];
          t[0] = f2bf(f0.x); t[1] = f2bf(f0.y); t[2] = f2bf(f0.z); t[3] = f2bf(f0.w);
          t[4] = f2bf(f1.x); t[5] = f2bf(f1.y); t[6] = f2bf(f1.z); t[7] = f2bf(f1.w);
          *reinterpret_cast<uint4*>(&As[r][kg * 8]) = *reinterpret_cast<const uint4*>(t);
        } else {
          uint4 vh = zero4;
          if (grow < M) vh = *reinterpret_cast<const uint4*>(&Ahi[(size_t)grow * K + k0 + kg * 8]);
          *reinterpret_cast<uint4*>(&As[r][kg * 8]) = vh;
        }
      }
    }
    {  // stage B hi
      int r = tid >> 2;
      const int kg = tid & 3;
#pragma unroll
      for (int it = 0; it < BN / 64; ++it, r += 64) {
        const int gcol = col0 + r;
        uint4 vh = *reinterpret_cast<const uint4*>(&BThi[(size_t)gcol * K + k0 + kg * 8]);
        *reinterpret_cast<uint4*>(&Bs[r][kg * 8]) = vh;
      }
    }
    __syncthreads();
    bf16x8 ah[4];
#pragma unroll
    for (int m = 0; m < 4; ++m) {
      const int row = wm * 64 + m * 16 + l15;
      ah[m] = *reinterpret_cast<const bf16x8*>(&As[row][lg * 8]);
    }
#pragma unroll
    for (int n = 0; n < NF; ++n) {
      const int col = wn * (NF * 16) + n * 16 + l15;
      bf16x8 bh = *reinterpret_cast<const bf16x8*>(&Bs[col][lg * 8]);
#pragma unroll
      for (int m = 0; m < 4; ++m)
        acc[m][n] = __builtin_amdgcn_mfma_f32_16x16x32_bf16(ah[m], bh, acc[m][n], 0, 0, 0);
    }
    __syncthreads();
  }
  const int hw = (col0 + wn * (NF * 16)) >> 6;
  float alw[NF], arw[NF];
#pragma unroll
  for (int n = 0; n < NF; ++n) {
    const int colg = col0 + wn * (NF * 16) + n * 16 + l15;
    alw[n] = alv[colg];
    arw[n] = arv[colg];
  }
  float pel[4][4] = {{0.f}}, per_[4][4] = {{0.f}};
#pragma unroll
  for (int m = 0; m < 4; ++m) {
#pragma unroll
    for (int n = 0; n < NF; ++n) {
      const int col = col0 + wn * (NF * 16) + n * 16 + l15;
#pragma unroll
      for (int j = 0; j < 4; ++j) {
        const int row = row0 + wm * 64 + m * 16 + lg * 4 + j;
        const float v = acc[m][n][j];
        if (row < M) {
          if constexpr (NF == 4) {
            Chi[(size_t)row * 256 + (col & 63) * 4 + (col >> 6)] = f2bf(v);
          } else {
            Chi[(size_t)row * Ncols + col] = f2bf(v);
          }
        }
        pel[m][j] = fmaf(v, alw[n], pel[m][j]);
        per_[m][j] = fmaf(v, arw[n], per_[m][j]);
      }
    }
  }
  float rl[4][4], rr[4][4];
#pragma unroll
  for (int m = 0; m < 4; ++m) {
#pragma unroll
    for (int j = 0; j < 4; ++j) {
      float vl = pel[m][j], vr = per_[m][j];
#pragma unroll
      for (int off = 1; off < 16; off <<= 1) {
        vl += __shfl_xor(vl, off);
        vr += __shfl_xor(vr, off);
      }
      rl[m][j] = vl; rr[m][j] = vr;
    }
  }
  if constexpr (NF == 4) {
    if (l15 == 0) {
#pragma unroll
      for (int m = 0; m < 4; ++m)
#pragma unroll
        for (int j = 0; j < 4; ++j) {
          const int row = row0 + wm * 64 + m * 16 + lg * 4 + j;
          if (row < M) {
            el[(size_t)row * 4 + hw] = rl[m][j];
            er[(size_t)row * 4 + hw] = rr[m][j];
          }
        }
    }
  } else {
    __shared__ float sl[128], sr[128];
    if (wn == 1 && l15 == 0) {
#pragma unroll
      for (int m = 0; m < 4; ++m)
#pragma unroll
        for (int j = 0; j < 4; ++j) {
          const int lr = wm * 64 + m * 16 + lg * 4 + j;
          sl[lr] = rl[m][j]; sr[lr] = rr[m][j];
        }
    }
    __syncthreads();
    if (wn == 0 && l15 == 0) {
#pragma unroll
      for (int m = 0; m < 4; ++m)
#pragma unroll
        for (int j = 0; j < 4; ++j) {
          const int lr = wm * 64 + m * 16 + lg * 4 + j;
          const int row = row0 + lr;
          if (row < M) {
            el[row] = rl[m][j] + sl[lr];
            er[row] = rr[m][j] + sr[lr];
          }
        }
    }
  }
}

// ---------------- CSR build ----------------
__global__ void hist_kernel(const int* __restrict__ dst, int* __restrict__ deg, int E) {
  int i = blockIdx.x * blockDim.x + threadIdx.x;
  if (i < E) atomicAdd(&deg[dst[i]], 1);
}

__global__ void scan1(const int* __restrict__ deg, int* __restrict__ offs,
                      int* __restrict__ bsums, int N) {
  __shared__ int tmp[256];
  const int tid = threadIdx.x;
  const int i = blockIdx.x * 256 + tid;
  int v = (i < N) ? deg[i] : 0;
  tmp[tid] = v;
  __syncthreads();
  for (int d = 1; d < 256; d <<= 1) {
    int t = (tid >= d) ? tmp[tid - d] : 0;
    __syncthreads();
    tmp[tid] += t;
    __syncthreads();
  }
  if (i < N) offs[i] = tmp[tid] - v;
  if (tid == 255) bsums[blockIdx.x] = tmp[255];
}

__global__ void scan2(int* __restrict__ bsums, int nb) {
  __shared__ int tmp[256];
  const int tid = threadIdx.x;
  int v = (tid < nb) ? bsums[tid] : 0;
  tmp[tid] = v;
  __syncthreads();
  for (int d = 1; d < 256; d <<= 1) {
    int t = (tid >= d) ? tmp[tid - d] : 0;
    __syncthreads();
    tmp[tid] += t;
    __syncthreads();
  }
  if (tid < nb) bsums[tid] = tmp[tid] - v;
}

__global__ void scan3(int* __restrict__ offs, const int* __restrict__ bsums,
                      int* __restrict__ cursor, int N, int E) {
  const int i = blockIdx.x * 256 + threadIdx.x;
  if (i < N) {
    const int v = offs[i] + bsums[blockIdx.x];
    offs[i] = v;
    cursor[i] = v;
  }
  if (i == 0) offs[N] = E;
}

__global__ void scatter_kernel(const int* __restrict__ src, const int* __restrict__ dst,
                               int* __restrict__ cursor, int* __restrict__ csr_src, int E) {
  int i = blockIdx.x * blockDim.x + threadIdx.x;
  if (i >= E) return;
  int pos = atomicAdd(&cursor[dst[i]], 1);
  csr_src[pos] = src[i];
}

// ---------------- fused alpha+aggregate H=4: one wave per node ----------------
// Phase 1: e-pass (online max/sum, e stashed in wave-private LDS up to CAP).
// Phase 1.5: alpha in LDS. Phase 2: 8-edge-unroll gather, alpha via ds_read broadcast.
#define CAP 128
__global__ void agg_fused_h4(const int* __restrict__ offs, const int* __restrict__ csr_src,
                             const ushort4* __restrict__ feat4, const float* __restrict__ el,
                             const float* __restrict__ er, const float* __restrict__ bias,
                             ushort4* __restrict__ out4, int N) {
  __shared__ float ea[4][CAP][4];
  const int wslot = threadIdx.x >> 6;
  const int node = (int)((blockIdx.x * (size_t)blockDim.x + threadIdx.x) >> 6);
  const int lane = threadIdx.x & 63;
  if (node >= N) return;
  const int beg = offs[node], end = offs[node + 1];
  const int deg = end - beg;
  const float4 erv = *reinterpret_cast<const float4*>(&er[(size_t)node * 4]);
  float m0 = -INFINITY, m1 = -INFINITY, m2 = -INFINITY, m3 = -INFINITY;
  float s0 = 0.f, s1 = 0.f, s2 = 0.f, s3 = 0.f;
  // phase 1
  for (int i0 = beg; i0 < end; i0 += 64) {
    const int i = i0 + lane;
    const bool valid = i < end;
    const int sn = valid ? csr_src[i] : 0;
    const float4 elv = *reinterpret_cast<const float4*>(&el[(size_t)sn * 4]);
    float e0 = elv.x + erv.x, e1 = elv.y + erv.y, e2 = elv.z + erv.z, e3 = elv.w + erv.w;
    e0 = e0 > 0.f ? e0 : NEG_SLOPE * e0;
    e1 = e1 > 0.f ? e1 : NEG_SLOPE * e1;
    e2 = e2 > 0.f ? e2 : NEG_SLOPE * e2;
    e3 = e3 > 0.f ? e3 : NEG_SLOPE * e3;
    if (!valid) { e0 = e1 = e2 = e3 = -INFINITY; }
    const int sidx = i0 - beg + lane;
    if (valid && sidx < CAP) {
      float4 ev; ev.x = e0; ev.y = e1; ev.z = e2; ev.w = e3;
      *reinterpret_cast<float4*>(&ea[wslot][sidx][0]) = ev;
    }
    float cm, cs, nm;
#define RED(eh, mh, sh)                                                  \
    cm = eh;                                                             \
    _Pragma("unroll")                                                    \
    for (int off = 1; off < 64; off <<= 1) cm = fmaxf(cm, __shfl_xor(cm, off)); \
    nm = fmaxf(mh, cm);                                                  \
    cs = __expf(eh - nm);                                                \
    _Pragma("unroll")                                                    \
    for (int off = 1; off < 64; off <<= 1) cs += __shfl_xor(cs, off);    \
    sh = sh * __expf(mh - nm) + cs;                                      \
    mh = nm;
    RED(e0, m0, s0) RED(e1, m1, s1) RED(e2, m2, s2) RED(e3, m3, s3)
#undef RED
  }
  const float i0v = 1.f / fmaxf(s0, 1e-9f);
  const float i1v = 1.f / fmaxf(s1, 1e-9f);
  const float i2v = 1.f / fmaxf(s2, 1e-9f);
  const float i3v = 1.f / fmaxf(s3, 1e-9f);
  // phase 1.5: e -> alpha in LDS (parallel over edges)
  const int cap = deg < CAP ? deg : CAP;
  for (int sidx = lane; sidx < cap; sidx += 64) {
    float4 ev = *reinterpret_cast<const float4*>(&ea[wslot][sidx][0]);
    float4 av;
    av.x = __expf(ev.x - m0) * i0v;
    av.y = __expf(ev.y - m1) * i1v;
    av.z = __expf(ev.z - m2) * i2v;
    av.w = __expf(ev.w - m3) * i3v;
    *reinterpret_cast<float4*>(&ea[wslot][sidx][0]) = av;
  }
  // overflow alpha (deg > CAP, rare): recompute from el
  auto alphaOf = [&](int sn) -> float4 {
    const float4 elv = *reinterpret_cast<const float4*>(&el[(size_t)sn * 4]);
    float e0x = elv.x + erv.x, e1x = elv.y + erv.y, e2x = elv.z + erv.z, e3x = elv.w + erv.w;
    e0x = e0x > 0.f ? e0x : NEG_SLOPE * e0x;
    e1x = e1x > 0.f ? e1x : NEG_SLOPE * e1x;
    e2x = e2x > 0.f ? e2x : NEG_SLOPE * e2x;
    e3x = e3x > 0.f ? e3x : NEG_SLOPE * e3x;
    float4 r;
    r.x = __expf(e0x - m0) * i0v; r.y = __expf(e1x - m1) * i1v;
    r.z = __expf(e2x - m2) * i2v; r.w = __expf(e3x - m3) * i3v;
    return r;
  };
  // phase 2: gather
  float a0 = 0.f, a1 = 0.f, a2 = 0.f, a3 = 0.f;
  int i = beg;
  for (; i + 7 < end; i += 8) {
    int sn[8]; float4 aw[8]; ushort4 uv[8];
#pragma unroll
    for (int u = 0; u < 8; ++u) sn[u] = csr_src[i + u];
#pragma unroll
    for (int u = 0; u < 8; ++u) {
      const int sidx = i + u - beg;
      aw[u] = (sidx < CAP) ? *reinterpret_cast<const float4*>(&ea[wslot][sidx][0])
                           : alphaOf(sn[u]);
    }
#pragma unroll
    for (int u = 0; u < 8; ++u) uv[u] = feat4[(size_t)sn[u] * 64 + lane];
#pragma unroll
    for (int u = 0; u < 8; ++u) {
      a0 = fmaf(aw[u].x, bf2f(uv[u].x), a0);
      a1 = fmaf(aw[u].y, bf2f(uv[u].y), a1);
      a2 = fmaf(aw[u].z, bf2f(uv[u].z), a2);
      a3 = fmaf(aw[u].w, bf2f(uv[u].w), a3);
    }
  }
  for (; i < end; ++i) {
    const int sn = csr_src[i];
    const int sidx = i - beg;
    const float4 aw = (sidx < CAP) ? *reinterpret_cast<const float4*>(&ea[wslot][sidx][0])
                                   : alphaOf(sn);
    const ushort4 uv = feat4[(size_t)sn * 64 + lane];
    a0 = fmaf(aw.x, bf2f(uv.x), a0);
    a1 = fmaf(aw.y, bf2f(uv.y), a1);
    a2 = fmaf(aw.z, bf2f(uv.z), a2);
    a3 = fmaf(aw.w, bf2f(uv.w), a3);
  }
  const float o0 = a0 + bias[lane];
  const float o1 = a1 + bias[64 + lane];
  const float o2 = a2 + bias[128 + lane];
  const float o3 = a3 + bias[192 + lane];
  ushort4 ov;
  ov.x = f2bf(o0); ov.y = f2bf(o1); ov.z = f2bf(o2); ov.w = f2bf(o3);
  out4[(size_t)node * 64 + lane] = ov;
}
#undef CAP

// ---------------- alpha H=1: 16-lane group per dst node (4 nodes/wave); abuf bf16 ----------------
__global__ void alpha16_h1(const int* __restrict__ offs, const int* __restrict__ csr_src,
                           const float* __restrict__ el, const float* __restrict__ er,
                           unsigned short* __restrict__ abuf, int N) {
  const int w = (int)((blockIdx.x * (size_t)blockDim.x + threadIdx.x) >> 6);
  const int lane = threadIdx.x & 63;
  const int g = lane >> 4, q = lane & 15;
  const int node = w * 4 + g;
  int beg = 0, end = 0;
  float erh = 0.f;
  if (node < N) { beg = offs[node]; end = offs[node + 1]; erh = er[node]; }
  float m = -INFINITY, s = 0.f;
  for (int i0 = beg; i0 < end; i0 += 16) {
    const int i = i0 + q;
    const bool valid = i < end;
    const int sn = valid ? csr_src[i] : 0;
    float e = el[sn] + erh;
    e = e > 0.f ? e : NEG_SLOPE * e;
    if (!valid) e = -INFINITY;
    float cm = e;
#pragma unroll
    for (int off = 1; off < 16; off <<= 1) cm = fmaxf(cm, __shfl_xor(cm, off));
    const float nm = fmaxf(m, cm);
    float cs = __expf(e - nm);
#pragma unroll
    for (int off = 1; off < 16; off <<= 1) cs += __shfl_xor(cs, off);
    s = s * __expf(m - nm) + cs;
    m = nm;
  }
  const float inv = 1.f / fmaxf(s, 1e-9f);
  for (int i0 = beg; i0 < end; i0 += 16) {
    const int i = i0 + q;
    if (i < end) {
      const int sn = csr_src[i];
      float e = el[sn] + erh;
      e = e > 0.f ? e : NEG_SLOPE * e;
      abuf[i] = f2bf(__expf(e - m) * inv);
    }
  }
}

// ---------------- aggregate H=1: 16-lane groups, 4 edges/iter ----------------
__global__ void aggregate1(const int* __restrict__ offs, const int* __restrict__ csr_src,
                           const unsigned short* __restrict__ featH, const unsigned short* __restrict__ abuf,
                           const float* __restrict__ bias, float* __restrict__ outf, int N) {
  const int wid = (int)((blockIdx.x * (size_t)blockDim.x + threadIdx.x) >> 6);
  const int lane = threadIdx.x & 63;
  if (wid >= N) return;
  const int beg = offs[wid], end = offs[wid + 1];
  const int g = lane >> 4, q = lane & 15;
  float4 acc = make_float4(0.f, 0.f, 0.f, 0.f);
  for (int i0 = beg; i0 < end; i0 += 4) {
    const int e = i0 + g;
    if (e < end) {
      const int sn = csr_src[e];
      const float a = bf2f(abuf[e]);
      const ushort4 u = *reinterpret_cast<const ushort4*>(&featH[(size_t)sn * 64 + q * 4]);
      acc.x = fmaf(a, bf2f(u.x), acc.x);
      acc.y = fmaf(a, bf2f(u.y), acc.y);
      acc.z = fmaf(a, bf2f(u.z), acc.z);
      acc.w = fmaf(a, bf2f(u.w), acc.w);
    }
  }
#pragma unroll
  for (int off = 16; off <= 32; off <<= 1) {
    acc.x += __shfl_xor(acc.x, off);
    acc.y += __shfl_xor(acc.y, off);
    acc.z += __shfl_xor(acc.z, off);
    acc.w += __shfl_xor(acc.w, off);
  }
  if (lane < 16) {
    const float4 b4 = *reinterpret_cast<const float4*>(&bias[q * 4]);
    float4 o = make_float4(acc.x + b4.x, acc.y + b4.y, acc.z + b4.z, acc.w + b4.w);
    *reinterpret_cast<float4*>(&outf[(size_t)wid * 64 + q * 4]) = o;
  }
}

// ---------------- tail: ids as float ----------------
__global__ void copy_ids(const int* __restrict__ ids, float* __restrict__ out, int n) {
  int i = blockIdx.x * blockDim.x + threadIdx.x;
  if (i < n) out[i] = (float)ids[i];
}

extern "C" void kernel_launch(void* const* d_in, const int* in_sizes, int n_in,
                              void* d_out, int out_size, void* d_ws, size_t ws_size,
                              hipStream_t stream) {
  const float* h   = (const float*)d_in[0];
  const int* src   = (const int*)d_in[1];
  const int* dst   = (const int*)d_in[2];
  const int* ids   = (const int*)d_in[3];
  const float* W0  = (const float*)d_in[4];
  const float* al0 = (const float*)d_in[5];
  const float* ar0 = (const float*)d_in[6];
  const float* b0  = (const float*)d_in[7];
  const float* W1  = (const float*)d_in[8];
  const float* al1 = (const float*)d_in[9];
  const float* ar1 = (const float*)d_in[10];
  const float* b1  = (const float*)d_in[11];
  const float* W2  = (const float*)d_in[12];
  const float* al2 = (const float*)d_in[13];
  const float* ar2 = (const float*)d_in[14];
  const float* b2  = (const float*)d_in[15];

  const int Din = 256, HF = 256, F2 = 64;
  const int N = in_sizes[0] / Din;        // 50000
  const int E = in_sizes[1];              // 800000
  const int NIDS = in_sizes[3];           // 1024

  // workspace layout (16B-aligned chunks)
  char* p = (char*)d_ws;
  unsigned short* Chi = (unsigned short*)p; p += (size_t)N * 256 * 2;
  unsigned short* Ahi = (unsigned short*)p; p += (size_t)N * 256 * 2;
  unsigned short* W0hi = (unsigned short*)p; p += (size_t)HF * Din * 2;
  unsigned short* W1hi = (unsigned short*)p; p += (size_t)HF * HF * 2;
  unsigned short* W2hi = (unsigned short*)p; p += (size_t)F2 * HF * 2;
  float* el   = (float*)p;             p += (size_t)N * 4 * 4;
  float* er   = (float*)p;             p += (size_t)N * 4 * 4;
  unsigned short* abuf = (unsigned short*)p; p += (size_t)E * 2;       // alpha bf16 (H=1 only)
  int* deg    = (int*)p;               p += (size_t)N * 4;             // also cursor
  int* offs   = (int*)p;               p += (size_t)(N + 16) * 4;
  int* bsums  = (int*)p;               p += 256 * 4;
  int* csr_src = (int*)p;              p += (size_t)E * 4;

  float* outp = (float*)d_out;
  dim3 blk(256);
  const int nb = cdiv(N, 256);

  // ---------------- weight splits (one launch) ----------------
  splitT_all<<<cdiv(256 * 256 * 2 + 256 * 64, 256), blk, 0, stream>>>(
      W0, W0hi, W1, W1hi, W2, W2hi);

  // ---------------- CSR build (shared by all 3 layers) ----------------
  hipMemsetAsync(deg, 0, (size_t)N * 4, stream);
  hist_kernel<<<cdiv(E, 256), blk, 0, stream>>>(dst, deg, E);
  scan1<<<nb, blk, 0, stream>>>(deg, offs, bsums, N);
  scan2<<<1, blk, 0, stream>>>(bsums, nb);
  scan3<<<nb, blk, 0, stream>>>(offs, bsums, deg, N, E);   // deg becomes cursor
  scatter_kernel<<<cdiv(E, 256), blk, 0, stream>>>(src, dst, deg, csr_src, E);

  // ---------------- layer 0 (H=4): h(f32) -> Chi(interleaved) -> Ahi(interleaved) ----------------
  {
    dim3 g(cdiv(N, 128), HF / 128);
    gemm_split<4, true><<<g, blk, 0, stream>>>(nullptr, h, W0hi, Chi, al0, ar0, el, er, 4, N, Din, HF);
    agg_fused_h4<<<cdiv(N * 64, 256), blk, 0, stream>>>(offs, csr_src, (const ushort4*)Chi,
                                                        el, er, b0, (ushort4*)Ahi, N);
  }
  // ---------------- layer 1 (H=4) ----------------
  {
    dim3 g(cdiv(N, 128), HF / 128);
    gemm_split<4, false><<<g, blk, 0, stream>>>(Ahi, nullptr, W1hi, Chi, al1, ar1, el, er, 4, N, HF, HF);
    agg_fused_h4<<<cdiv(N * 64, 256), blk, 0, stream>>>(offs, csr_src, (const ushort4*)Chi,
                                                        el, er, b1, (ushort4*)Ahi, N);
  }
  // ---------------- layer 2 (H=1): -> d_out (standard layout) ----------------
  {
    dim3 g(cdiv(N, 128), 1);
    gemm_split<2, false><<<g, blk, 0, stream>>>(Ahi, nullptr, W2hi, Chi, al2, ar2, el, er, 1, N, HF, F2);
    alpha16_h1<<<cdiv(cdiv(N, 4) * 64, 256), blk, 0, stream>>>(offs, csr_src, el, er, abuf, N);
    aggregate1<<<cdiv(N * 64, 256), blk, 0, stream>>>(offs, csr_src, Chi, abuf, b2, outp, N);
  }
  // ---------------- tail ids ----------------
  copy_ids<<<cdiv(NIDS, 256), blk, 0, stream>>>(ids, outp + (size_t)N * F2, NIDS);
}

// Round 12
// 389.314 us; speedup vs baseline: 1.1291x; 1.1291x over previous
//
#include <hip/hip_runtime.h>
#include <hip/hip_bf16.h>

#define NEG_SLOPE 0.2f

typedef __attribute__((ext_vector_type(8))) short bf16x8;
typedef __attribute__((ext_vector_type(4))) float f32x4;

static inline int cdiv(int a, int b) { return (a + b - 1) / b; }

__device__ inline unsigned short f2bf(float x) {
  __hip_bfloat16 b = __float2bfloat16(x);
  return *reinterpret_cast<unsigned short*>(&b);
}
__device__ inline float bf2f(unsigned short u) {
  unsigned int v = (unsigned int)u << 16;
  return *reinterpret_cast<float*>(&v);
}

// ---------------- fused split+transpose (bf16 hi only) for all 3 weights ----------------
// W[K][Mo] -> T[Mo][K]; W1/W2 get k-permutation pi(k)=(k&63)*4+(k>>6)
__global__ void splitT_all(const float* __restrict__ W0, unsigned short* __restrict__ W0hi,
                           const float* __restrict__ W1, unsigned short* __restrict__ W1hi,
                           const float* __restrict__ W2, unsigned short* __restrict__ W2hi) {
  const int S0 = 256 * 256, S1 = 256 * 256, S2 = 256 * 64;
  int i = blockIdx.x * blockDim.x + threadIdx.x;
  const float* W; unsigned short* hi; int K, Mo, perm;
  if (i < S0) { W = W0; hi = W0hi; K = 256; Mo = 256; perm = 0; }
  else if (i < S0 + S1) { i -= S0; W = W1; hi = W1hi; K = 256; Mo = 256; perm = 1; }
  else if (i < S0 + S1 + S2) { i -= S0 + S1; W = W2; hi = W2hi; K = 256; Mo = 64; perm = 1; }
  else return;
  int k = i / Mo, m = i - k * Mo;
  int kk = perm ? ((k & 63) * 4 + (k >> 6)) : k;
  hi[(size_t)m * K + kk] = f2bf(W[i]);
}

// ---------------- GEMM (single bf16 MFMA) + fused attention-score partials ----------------
// CVT: stage A from f32 source. NF=4: Chi HEAD-INTERLEAVED, el/er plain store.
// NF=2: Chi standard, el/er cross-wave LDS reduce + plain store.
template <int NF, bool CVT>
__global__ __launch_bounds__(256) void gemm_split(
    const unsigned short* __restrict__ Ahi, const float* __restrict__ Af32,
    const unsigned short* __restrict__ BThi,
    unsigned short* __restrict__ Chi,
    const float* __restrict__ alv, const float* __restrict__ arv,
    float* __restrict__ el, float* __restrict__ er, int Hn, int M, int K, int Ncols) {
  constexpr int BN = NF * 32;
  __shared__ unsigned short As[128][40];
  __shared__ unsigned short Bs[BN][40];
  const int tid = threadIdx.x;
  const int row0 = blockIdx.x * 128;
  const int col0 = blockIdx.y * BN;
  const int wid = tid >> 6, lane = tid & 63;
  const int wm = wid >> 1, wn = wid & 1;
  const int l15 = lane & 15, lg = lane >> 4;
  f32x4 acc[4][NF];
#pragma unroll
  for (int m = 0; m < 4; ++m)
#pragma unroll
    for (int n = 0; n < NF; ++n) acc[m][n] = (f32x4){0.f, 0.f, 0.f, 0.f};

  const uint4 zero4 = {0u, 0u, 0u, 0u};
  for (int k0 = 0; k0 < K; k0 += 32) {
    {  // stage A
      int r = tid >> 2;
      const int kg = tid & 3;
#pragma unroll
      for (int it = 0; it < 2; ++it, r += 64) {
        const int grow = row0 + r;
        if constexpr (CVT) {
          float4 f0 = make_float4(0.f, 0.f, 0.f, 0.f), f1 = f0;
          if (grow < M) {
            f0 = *reinterpret_cast<const float4*>(&Af32[(size_t)grow * K + k0 + kg * 8]);
            f1 = *reinterpret_cast<const float4*>(&Af32[(size_t)grow * K + k0 + kg * 8 + 4]);
          }
          unsigned short t[8];
          t[0] = f2bf(f0.x); t[1] = f2bf(f0.y); t[2] = f2bf(f0.z); t[3] = f2bf(f0.w);
          t[4] = f2bf(f1.x); t[5] = f2bf(f1.y); t[6] = f2bf(f1.z); t[7] = f2bf(f1.w);
          *reinterpret_cast<uint4*>(&As[r][kg * 8]) = *reinterpret_cast<const uint4*>(t);
        } else {
          uint4 vh = zero4;
          if (grow < M) vh = *reinterpret_cast<const uint4*>(&Ahi[(size_t)grow * K + k0 + kg * 8]);
          *reinterpret_cast<uint4*>(&As[r][kg * 8]) = vh;
        }
      }
    }
    {  // stage B hi
      int r = tid >> 2;
      const int kg = tid & 3;
#pragma unroll
      for (int it = 0; it < BN / 64; ++it, r += 64) {
        const int gcol = col0 + r;
        uint4 vh = *reinterpret_cast<const uint4*>(&BThi[(size_t)gcol * K + k0 + kg * 8]);
        *reinterpret_cast<uint4*>(&Bs[r][kg * 8]) = vh;
      }
    }
    __syncthreads();
    bf16x8 ah[4];
#pragma unroll
    for (int m = 0; m < 4; ++m) {
      const int row = wm * 64 + m * 16 + l15;
      ah[m] = *reinterpret_cast<const bf16x8*>(&As[row][lg * 8]);
    }
#pragma unroll
    for (int n = 0; n < NF; ++n) {
      const int col = wn * (NF * 16) + n * 16 + l15;
      bf16x8 bh = *reinterpret_cast<const bf16x8*>(&Bs[col][lg * 8]);
#pragma unroll
      for (int m = 0; m < 4; ++m)
        acc[m][n] = __builtin_amdgcn_mfma_f32_16x16x32_bf16(ah[m], bh, acc[m][n], 0, 0, 0);
    }
    __syncthreads();
  }
  const int hw = (col0 + wn * (NF * 16)) >> 6;
  float alw[NF], arw[NF];
#pragma unroll
  for (int n = 0; n < NF; ++n) {
    const int colg = col0 + wn * (NF * 16) + n * 16 + l15;
    alw[n] = alv[colg];
    arw[n] = arv[colg];
  }
  float pel[4][4] = {{0.f}}, per_[4][4] = {{0.f}};
#pragma unroll
  for (int m = 0; m < 4; ++m) {
#pragma unroll
    for (int n = 0; n < NF; ++n) {
      const int col = col0 + wn * (NF * 16) + n * 16 + l15;
#pragma unroll
      for (int j = 0; j < 4; ++j) {
        const int row = row0 + wm * 64 + m * 16 + lg * 4 + j;
        const float v = acc[m][n][j];
        if (row < M) {
          if constexpr (NF == 4) {
            Chi[(size_t)row * 256 + (col & 63) * 4 + (col >> 6)] = f2bf(v);
          } else {
            Chi[(size_t)row * Ncols + col] = f2bf(v);
          }
        }
        pel[m][j] = fmaf(v, alw[n], pel[m][j]);
        per_[m][j] = fmaf(v, arw[n], per_[m][j]);
      }
    }
  }
  float rl[4][4], rr[4][4];
#pragma unroll
  for (int m = 0; m < 4; ++m) {
#pragma unroll
    for (int j = 0; j < 4; ++j) {
      float vl = pel[m][j], vr = per_[m][j];
#pragma unroll
      for (int off = 1; off < 16; off <<= 1) {
        vl += __shfl_xor(vl, off);
        vr += __shfl_xor(vr, off);
      }
      rl[m][j] = vl; rr[m][j] = vr;
    }
  }
  if constexpr (NF == 4) {
    if (l15 == 0) {
#pragma unroll
      for (int m = 0; m < 4; ++m)
#pragma unroll
        for (int j = 0; j < 4; ++j) {
          const int row = row0 + wm * 64 + m * 16 + lg * 4 + j;
          if (row < M) {
            el[(size_t)row * 4 + hw] = rl[m][j];
            er[(size_t)row * 4 + hw] = rr[m][j];
          }
        }
    }
  } else {
    __shared__ float sl[128], sr[128];
    if (wn == 1 && l15 == 0) {
#pragma unroll
      for (int m = 0; m < 4; ++m)
#pragma unroll
        for (int j = 0; j < 4; ++j) {
          const int lr = wm * 64 + m * 16 + lg * 4 + j;
          sl[lr] = rl[m][j]; sr[lr] = rr[m][j];
        }
    }
    __syncthreads();
    if (wn == 0 && l15 == 0) {
#pragma unroll
      for (int m = 0; m < 4; ++m)
#pragma unroll
        for (int j = 0; j < 4; ++j) {
          const int lr = wm * 64 + m * 16 + lg * 4 + j;
          const int row = row0 + lr;
          if (row < M) {
            el[row] = rl[m][j] + sl[lr];
            er[row] = rr[m][j] + sr[lr];
          }
        }
    }
  }
}

// ---------------- CSR build ----------------
__global__ void hist_kernel(const int* __restrict__ dst, int* __restrict__ deg, int E) {
  int i = blockIdx.x * blockDim.x + threadIdx.x;
  if (i < E) atomicAdd(&deg[dst[i]], 1);
}

__global__ void scan1(const int* __restrict__ deg, int* __restrict__ offs,
                      int* __restrict__ bsums, int N) {
  __shared__ int tmp[256];
  const int tid = threadIdx.x;
  const int i = blockIdx.x * 256 + tid;
  int v = (i < N) ? deg[i] : 0;
  tmp[tid] = v;
  __syncthreads();
  for (int d = 1; d < 256; d <<= 1) {
    int t = (tid >= d) ? tmp[tid - d] : 0;
    __syncthreads();
    tmp[tid] += t;
    __syncthreads();
  }
  if (i < N) offs[i] = tmp[tid] - v;
  if (tid == 255) bsums[blockIdx.x] = tmp[255];
}

__global__ void scan2(int* __restrict__ bsums, int nb) {
  __shared__ int tmp[256];
  const int tid = threadIdx.x;
  int v = (tid < nb) ? bsums[tid] : 0;
  tmp[tid] = v;
  __syncthreads();
  for (int d = 1; d < 256; d <<= 1) {
    int t = (tid >= d) ? tmp[tid - d] : 0;
    __syncthreads();
    tmp[tid] += t;
    __syncthreads();
  }
  if (tid < nb) bsums[tid] = tmp[tid] - v;
}

__global__ void scan3(int* __restrict__ offs, const int* __restrict__ bsums,
                      int* __restrict__ cursor, int N, int E) {
  const int i = blockIdx.x * 256 + threadIdx.x;
  if (i < N) {
    const int v = offs[i] + bsums[blockIdx.x];
    offs[i] = v;
    cursor[i] = v;
  }
  if (i == 0) offs[N] = E;
}

__global__ void scatter_kernel(const int* __restrict__ src, const int* __restrict__ dst,
                               int* __restrict__ cursor, int* __restrict__ csr_src, int E) {
  int i = blockIdx.x * blockDim.x + threadIdx.x;
  if (i >= E) return;
  int pos = atomicAdd(&cursor[dst[i]], 1);
  csr_src[pos] = src[i];
}

// ---------------- alpha: 16-lane group per dst node (4 nodes/wave); abuf bf16 ----------------
template <int H>
__global__ void alpha16(const int* __restrict__ offs, const int* __restrict__ csr_src,
                        const float* __restrict__ el, const float* __restrict__ er,
                        unsigned short* __restrict__ abuf, int N) {
  const int w = (int)((blockIdx.x * (size_t)blockDim.x + threadIdx.x) >> 6);
  const int lane = threadIdx.x & 63;
  const int g = lane >> 4, q = lane & 15;
  const int node = w * 4 + g;
  int beg = 0, end = 0;
  float erh[H];
#pragma unroll
  for (int h = 0; h < H; ++h) erh[h] = 0.f;
  if (node < N) {
    beg = offs[node]; end = offs[node + 1];
    if constexpr (H == 4) {
      float4 t = *reinterpret_cast<const float4*>(&er[(size_t)node * 4]);
      erh[0] = t.x; erh[1] = t.y; erh[2] = t.z; erh[3] = t.w;
    } else {
      erh[0] = er[node];
    }
  }
  float m[H], s[H];
#pragma unroll
  for (int h = 0; h < H; ++h) { m[h] = -INFINITY; s[h] = 0.f; }
  for (int i0 = beg; i0 < end; i0 += 16) {
    const int i = i0 + q;
    const bool valid = i < end;
    const int sn = valid ? csr_src[i] : 0;
    float e[H];
    if constexpr (H == 4) {
      float4 v = *reinterpret_cast<const float4*>(&el[(size_t)sn * 4]);
      e[0] = v.x + erh[0]; e[1] = v.y + erh[1]; e[2] = v.z + erh[2]; e[3] = v.w + erh[3];
    } else {
      e[0] = el[sn] + erh[0];
    }
#pragma unroll
    for (int h = 0; h < H; ++h) {
      e[h] = e[h] > 0.f ? e[h] : NEG_SLOPE * e[h];
      if (!valid) e[h] = -INFINITY;
      float cm = e[h];
#pragma unroll
      for (int off = 1; off < 16; off <<= 1) cm = fmaxf(cm, __shfl_xor(cm, off));
      const float nm = fmaxf(m[h], cm);
      float cs = __expf(e[h] - nm);
#pragma unroll
      for (int off = 1; off < 16; off <<= 1) cs += __shfl_xor(cs, off);
      s[h] = s[h] * __expf(m[h] - nm) + cs;
      m[h] = nm;
    }
  }
  float inv[H];
#pragma unroll
  for (int h = 0; h < H; ++h) inv[h] = 1.f / fmaxf(s[h], 1e-9f);
  for (int i0 = beg; i0 < end; i0 += 16) {
    const int i = i0 + q;
    if (i < end) {
      const int sn = csr_src[i];
      float e[H];
      if constexpr (H == 4) {
        float4 v = *reinterpret_cast<const float4*>(&el[(size_t)sn * 4]);
        e[0] = v.x + erh[0]; e[1] = v.y + erh[1]; e[2] = v.z + erh[2]; e[3] = v.w + erh[3];
      } else {
        e[0] = el[sn] + erh[0];
      }
#pragma unroll
      for (int h = 0; h < H; ++h) {
        e[h] = e[h] > 0.f ? e[h] : NEG_SLOPE * e[h];
        e[h] = __expf(e[h] - m[h]) * inv[h];
      }
      if constexpr (H == 4) {
        ushort4 o;
        o.x = f2bf(e[0]); o.y = f2bf(e[1]); o.z = f2bf(e[2]); o.w = f2bf(e[3]);
        *reinterpret_cast<ushort4*>(&abuf[(size_t)i * 4]) = o;
      } else {
        abuf[i] = f2bf(e[0]);
      }
    }
  }
}

// ---------------- aggregate H=4: one wave/node, HEAD-INTERLEAVED ushort4 gather, 8-edge unroll ----------------
__global__ void aggregate_h4(const int* __restrict__ offs, const int* __restrict__ csr_src,
                             const ushort4* __restrict__ feat4, const ushort4* __restrict__ abuf4,
                             const float* __restrict__ bias, ushort4* __restrict__ out4, int N) {
  const int node = (int)((blockIdx.x * (size_t)blockDim.x + threadIdx.x) >> 6);
  const int lane = threadIdx.x & 63;
  if (node >= N) return;
  const int beg = offs[node], end = offs[node + 1];
  float a0 = 0.f, a1 = 0.f, a2 = 0.f, a3 = 0.f;
  int i = beg;
  for (; i + 7 < end; i += 8) {
    int sn[8]; ushort4 w[8]; ushort4 uv[8];
#pragma unroll
    for (int u = 0; u < 8; ++u) sn[u] = csr_src[i + u];
#pragma unroll
    for (int u = 0; u < 8; ++u) w[u] = abuf4[i + u];
#pragma unroll
    for (int u = 0; u < 8; ++u) uv[u] = feat4[(size_t)sn[u] * 64 + lane];
#pragma unroll
    for (int u = 0; u < 8; ++u) {
      a0 = fmaf(bf2f(w[u].x), bf2f(uv[u].x), a0);
      a1 = fmaf(bf2f(w[u].y), bf2f(uv[u].y), a1);
      a2 = fmaf(bf2f(w[u].z), bf2f(uv[u].z), a2);
      a3 = fmaf(bf2f(w[u].w), bf2f(uv[u].w), a3);
    }
  }
  for (; i < end; ++i) {
    const int sn = csr_src[i];
    const ushort4 w = abuf4[i];
    const ushort4 uv = feat4[(size_t)sn * 64 + lane];
    a0 = fmaf(bf2f(w.x), bf2f(uv.x), a0);
    a1 = fmaf(bf2f(w.y), bf2f(uv.y), a1);
    a2 = fmaf(bf2f(w.z), bf2f(uv.z), a2);
    a3 = fmaf(bf2f(w.w), bf2f(uv.w), a3);
  }
  const float o0 = a0 + bias[lane];
  const float o1 = a1 + bias[64 + lane];
  const float o2 = a2 + bias[128 + lane];
  const float o3 = a3 + bias[192 + lane];
  ushort4 ov;
  ov.x = f2bf(o0); ov.y = f2bf(o1); ov.z = f2bf(o2); ov.w = f2bf(o3);
  out4[(size_t)node * 64 + lane] = ov;
}

// ---------------- aggregate H=1: 16-lane groups, 4 edges/iter ----------------
__global__ void aggregate1(const int* __restrict__ offs, const int* __restrict__ csr_src,
                           const unsigned short* __restrict__ featH, const unsigned short* __restrict__ abuf,
                           const float* __restrict__ bias, float* __restrict__ outf, int N) {
  const int wid = (int)((blockIdx.x * (size_t)blockDim.x + threadIdx.x) >> 6);
  const int lane = threadIdx.x & 63;
  if (wid >= N) return;
  const int beg = offs[wid], end = offs[wid + 1];
  const int g = lane >> 4, q = lane & 15;
  float4 acc = make_float4(0.f, 0.f, 0.f, 0.f);
  for (int i0 = beg; i0 < end; i0 += 4) {
    const int e = i0 + g;
    if (e < end) {
      const int sn = csr_src[e];
      const float a = bf2f(abuf[e]);
      const ushort4 u = *reinterpret_cast<const ushort4*>(&featH[(size_t)sn * 64 + q * 4]);
      acc.x = fmaf(a, bf2f(u.x), acc.x);
      acc.y = fmaf(a, bf2f(u.y), acc.y);
      acc.z = fmaf(a, bf2f(u.z), acc.z);
      acc.w = fmaf(a, bf2f(u.w), acc.w);
    }
  }
#pragma unroll
  for (int off = 16; off <= 32; off <<= 1) {
    acc.x += __shfl_xor(acc.x, off);
    acc.y += __shfl_xor(acc.y, off);
    acc.z += __shfl_xor(acc.z, off);
    acc.w += __shfl_xor(acc.w, off);
  }
  if (lane < 16) {
    const float4 b4 = *reinterpret_cast<const float4*>(&bias[q * 4]);
    float4 o = make_float4(acc.x + b4.x, acc.y + b4.y, acc.z + b4.z, acc.w + b4.w);
    *reinterpret_cast<float4*>(&outf[(size_t)wid * 64 + q * 4]) = o;
  }
}

// ---------------- tail: ids as float ----------------
__global__ void copy_ids(const int* __restrict__ ids, float* __restrict__ out, int n) {
  int i = blockIdx.x * blockDim.x + threadIdx.x;
  if (i < n) out[i] = (float)ids[i];
}

extern "C" void kernel_launch(void* const* d_in, const int* in_sizes, int n_in,
                              void* d_out, int out_size, void* d_ws, size_t ws_size,
                              hipStream_t stream) {
  const float* h   = (const float*)d_in[0];
  const int* src   = (const int*)d_in[1];
  const int* dst   = (const int*)d_in[2];
  const int* ids   = (const int*)d_in[3];
  const float* W0  = (const float*)d_in[4];
  const float* al0 = (const float*)d_in[5];
  const float* ar0 = (const float*)d_in[6];
  const float* b0  = (const float*)d_in[7];
  const float* W1  = (const float*)d_in[8];
  const float* al1 = (const float*)d_in[9];
  const float* ar1 = (const float*)d_in[10];
  const float* b1  = (const float*)d_in[11];
  const float* W2  = (const float*)d_in[12];
  const float* al2 = (const float*)d_in[13];
  const float* ar2 = (const float*)d_in[14];
  const float* b2  = (const float*)d_in[15];

  const int Din = 256, HF = 256, F2 = 64;
  const int N = in_sizes[0] / Din;        // 50000
  const int E = in_sizes[1];              // 800000
  const int NIDS = in_sizes[3];           // 1024

  // workspace layout (16B-aligned chunks)
  char* p = (char*)d_ws;
  unsigned short* Chi = (unsigned short*)p; p += (size_t)N * 256 * 2;
  unsigned short* Ahi = (unsigned short*)p; p += (size_t)N * 256 * 2;
  unsigned short* W0hi = (unsigned short*)p; p += (size_t)HF * Din * 2;
  unsigned short* W1hi = (unsigned short*)p; p += (size_t)HF * HF * 2;
  unsigned short* W2hi = (unsigned short*)p; p += (size_t)F2 * HF * 2;
  float* el   = (float*)p;             p += (size_t)N * 4 * 4;
  float* er   = (float*)p;             p += (size_t)N * 4 * 4;
  unsigned short* abuf = (unsigned short*)p; p += (size_t)E * 4 * 2;   // alpha bf16
  int* deg    = (int*)p;               p += (size_t)N * 4;             // also cursor
  int* offs   = (int*)p;               p += (size_t)(N + 16) * 4;
  int* bsums  = (int*)p;               p += 256 * 4;
  int* csr_src = (int*)p;              p += (size_t)E * 4;

  float* outp = (float*)d_out;
  dim3 blk(256);
  const int nb = cdiv(N, 256);
  const int nwAlpha = cdiv(cdiv(N, 4) * 64, 256);

  // ---------------- weight splits (one launch) ----------------
  splitT_all<<<cdiv(256 * 256 * 2 + 256 * 64, 256), blk, 0, stream>>>(
      W0, W0hi, W1, W1hi, W2, W2hi);

  // ---------------- CSR build (shared by all 3 layers) ----------------
  hipMemsetAsync(deg, 0, (size_t)N * 4, stream);
  hist_kernel<<<cdiv(E, 256), blk, 0, stream>>>(dst, deg, E);
  scan1<<<nb, blk, 0, stream>>>(deg, offs, bsums, N);
  scan2<<<1, blk, 0, stream>>>(bsums, nb);
  scan3<<<nb, blk, 0, stream>>>(offs, bsums, deg, N, E);   // deg becomes cursor
  scatter_kernel<<<cdiv(E, 256), blk, 0, stream>>>(src, dst, deg, csr_src, E);

  // ---------------- layer 0 (H=4): h(f32) -> Chi(interleaved) -> Ahi(interleaved) ----------------
  {
    dim3 g(cdiv(N, 128), HF / 128);
    gemm_split<4, true><<<g, blk, 0, stream>>>(nullptr, h, W0hi, Chi, al0, ar0, el, er, 4, N, Din, HF);
    alpha16<4><<<nwAlpha, blk, 0, stream>>>(offs, csr_src, el, er, abuf, N);
    aggregate_h4<<<cdiv(N * 64, 256), blk, 0, stream>>>(offs, csr_src, (const ushort4*)Chi,
                                                        (const ushort4*)abuf, b0, (ushort4*)Ahi, N);
  }
  // ---------------- layer 1 (H=4) ----------------
  {
    dim3 g(cdiv(N, 128), HF / 128);
    gemm_split<4, false><<<g, blk, 0, stream>>>(Ahi, nullptr, W1hi, Chi, al1, ar1, el, er, 4, N, HF, HF);
    alpha16<4><<<nwAlpha, blk, 0, stream>>>(offs, csr_src, el, er, abuf, N);
    aggregate_h4<<<cdiv(N * 64, 256), blk, 0, stream>>>(offs, csr_src, (const ushort4*)Chi,
                                                        (const ushort4*)abuf, b1, (ushort4*)Ahi, N);
  }
  // ---------------- layer 2 (H=1): -> d_out (standard layout) ----------------
  {
    dim3 g(cdiv(N, 128), 1);
    gemm_split<2, false><<<g, blk, 0, stream>>>(Ahi, nullptr, W2hi, Chi, al2, ar2, el, er, 1, N, HF, F2);
    alpha16<1><<<nwAlpha, blk, 0, stream>>>(offs, csr_src, el, er, abuf, N);
    aggregate1<<<cdiv(N * 64, 256), blk, 0, stream>>>(offs, csr_src, Chi, abuf, b2, outp, N);
  }
  // ---------------- tail ids ----------------
  copy_ids<<<cdiv(NIDS, 256), blk, 0, stream>>>(ids, outp + (size_t)N * F2, NIDS);
}

// Round 13
// 361.787 us; speedup vs baseline: 1.2151x; 1.0761x over previous
//
#include <hip/hip_runtime.h>
#include <hip/hip_bf16.h>

#define NEG_SLOPE 0.2f

typedef __attribute__((ext_vector_type(8))) short bf16x8;
typedef __attribute__((ext_vector_type(4))) float f32x4;

static inline int cdiv(int a, int b) { return (a + b - 1) / b; }

__device__ inline unsigned short f2bf(float x) {
  __hip_bfloat16 b = __float2bfloat16(x);
  return *reinterpret_cast<unsigned short*>(&b);
}
__device__ inline float bf2f(unsigned short u) {
  unsigned int v = (unsigned int)u << 16;
  return *reinterpret_cast<float*>(&v);
}

// ---------------- fused split+transpose (bf16 hi only) for all 3 weights ----------------
// W[K][Mo] -> T[Mo][K]; W1/W2 get k-permutation pi(k)=(k&63)*4+(k>>6)
__global__ void splitT_all(const float* __restrict__ W0, unsigned short* __restrict__ W0hi,
                           const float* __restrict__ W1, unsigned short* __restrict__ W1hi,
                           const float* __restrict__ W2, unsigned short* __restrict__ W2hi) {
  const int S0 = 256 * 256, S1 = 256 * 256, S2 = 256 * 64;
  int i = blockIdx.x * blockDim.x + threadIdx.x;
  const float* W; unsigned short* hi; int K, Mo, perm;
  if (i < S0) { W = W0; hi = W0hi; K = 256; Mo = 256; perm = 0; }
  else if (i < S0 + S1) { i -= S0; W = W1; hi = W1hi; K = 256; Mo = 256; perm = 1; }
  else if (i < S0 + S1 + S2) { i -= S0 + S1; W = W2; hi = W2hi; K = 256; Mo = 64; perm = 1; }
  else return;
  int k = i / Mo, m = i - k * Mo;
  int kk = perm ? ((k & 63) * 4 + (k >> 6)) : k;
  hi[(size_t)m * K + kk] = f2bf(W[i]);
}

// ---------------- GEMM (single bf16 MFMA) + fused score partials ----------------
// NF=4: output INT8 messages Cq[row][f=col&63][h=col>>6] with per-(row,head) scale;
//       elsc[row*8+h]=el, elsc[row*8+4+h]=scale; er4[row*4+h]=er (plain stores).
// NF=2: Chi bf16 standard layout; el1/er1 via cross-wave LDS reduce + plain store.
template <int NF, bool CVT>
__global__ __launch_bounds__(256) void gemm_split(
    const unsigned short* __restrict__ Ahi, const float* __restrict__ Af32,
    const unsigned short* __restrict__ BThi,
    unsigned short* __restrict__ Chi, signed char* __restrict__ Cq,
    const float* __restrict__ alv, const float* __restrict__ arv,
    float* __restrict__ elsc, float* __restrict__ er4,
    float* __restrict__ el1, float* __restrict__ er1,
    int M, int K, int Ncols) {
  constexpr int BN = NF * 32;
  __shared__ unsigned short As[128][40];
  __shared__ unsigned short Bs[BN][40];
  const int tid = threadIdx.x;
  const int row0 = blockIdx.x * 128;
  const int col0 = blockIdx.y * BN;
  const int wid = tid >> 6, lane = tid & 63;
  const int wm = wid >> 1, wn = wid & 1;
  const int l15 = lane & 15, lg = lane >> 4;
  f32x4 acc[4][NF];
#pragma unroll
  for (int m = 0; m < 4; ++m)
#pragma unroll
    for (int n = 0; n < NF; ++n) acc[m][n] = (f32x4){0.f, 0.f, 0.f, 0.f};

  const uint4 zero4 = {0u, 0u, 0u, 0u};
  for (int k0 = 0; k0 < K; k0 += 32) {
    {  // stage A
      int r = tid >> 2;
      const int kg = tid & 3;
#pragma unroll
      for (int it = 0; it < 2; ++it, r += 64) {
        const int grow = row0 + r;
        if constexpr (CVT) {
          float4 f0 = make_float4(0.f, 0.f, 0.f, 0.f), f1 = f0;
          if (grow < M) {
            f0 = *reinterpret_cast<const float4*>(&Af32[(size_t)grow * K + k0 + kg * 8]);
            f1 = *reinterpret_cast<const float4*>(&Af32[(size_t)grow * K + k0 + kg * 8 + 4]);
          }
          unsigned short t[8];
          t[0] = f2bf(f0.x); t[1] = f2bf(f0.y); t[2] = f2bf(f0.z); t[3] = f2bf(f0.w);
          t[4] = f2bf(f1.x); t[5] = f2bf(f1.y); t[6] = f2bf(f1.z); t[7] = f2bf(f1.w);
          *reinterpret_cast<uint4*>(&As[r][kg * 8]) = *reinterpret_cast<const uint4*>(t);
        } else {
          uint4 vh = zero4;
          if (grow < M) vh = *reinterpret_cast<const uint4*>(&Ahi[(size_t)grow * K + k0 + kg * 8]);
          *reinterpret_cast<uint4*>(&As[r][kg * 8]) = vh;
        }
      }
    }
    {  // stage B hi
      int r = tid >> 2;
      const int kg = tid & 3;
#pragma unroll
      for (int it = 0; it < BN / 64; ++it, r += 64) {
        const int gcol = col0 + r;
        uint4 vh = *reinterpret_cast<const uint4*>(&BThi[(size_t)gcol * K + k0 + kg * 8]);
        *reinterpret_cast<uint4*>(&Bs[r][kg * 8]) = vh;
      }
    }
    __syncthreads();
    bf16x8 ah[4];
#pragma unroll
    for (int m = 0; m < 4; ++m) {
      const int row = wm * 64 + m * 16 + l15;
      ah[m] = *reinterpret_cast<const bf16x8*>(&As[row][lg * 8]);
    }
#pragma unroll
    for (int n = 0; n < NF; ++n) {
      const int col = wn * (NF * 16) + n * 16 + l15;
      bf16x8 bh = *reinterpret_cast<const bf16x8*>(&Bs[col][lg * 8]);
#pragma unroll
      for (int m = 0; m < 4; ++m)
        acc[m][n] = __builtin_amdgcn_mfma_f32_16x16x32_bf16(ah[m], bh, acc[m][n], 0, 0, 0);
    }
    __syncthreads();
  }
  const int hw = (col0 + wn * (NF * 16)) >> 6;
  float alw[NF], arw[NF];
#pragma unroll
  for (int n = 0; n < NF; ++n) {
    const int colg = col0 + wn * (NF * 16) + n * 16 + l15;
    alw[n] = alv[colg];
    arw[n] = arv[colg];
  }

  if constexpr (NF == 4) {
    // per-(m,j): el/er partials + head max, reduced over l15 (wave holds full head-row)
#pragma unroll
    for (int m = 0; m < 4; ++m) {
#pragma unroll
      for (int j = 0; j < 4; ++j) {
        float mx = 0.f, vl = 0.f, vr = 0.f;
#pragma unroll
        for (int n = 0; n < 4; ++n) {
          const float v = acc[m][n][j];
          mx = fmaxf(mx, fabsf(v));
          vl = fmaf(v, alw[n], vl);
          vr = fmaf(v, arw[n], vr);
        }
#pragma unroll
        for (int off = 1; off < 16; off <<= 1) {
          mx = fmaxf(mx, __shfl_xor(mx, off));
          vl += __shfl_xor(vl, off);
          vr += __shfl_xor(vr, off);
        }
        const int row = row0 + wm * 64 + m * 16 + lg * 4 + j;
        if (row < M) {
          const float rinv = mx > 0.f ? 127.f / mx : 0.f;
#pragma unroll
          for (int n = 0; n < 4; ++n) {
            const int f = n * 16 + l15;
            const int q = __float2int_rn(acc[m][n][j] * rinv);
            Cq[(size_t)row * 256 + (f << 2) + hw] = (signed char)q;
          }
          if (l15 == 0) {
            elsc[(size_t)row * 8 + hw] = vl;
            elsc[(size_t)row * 8 + 4 + hw] = mx * (1.f / 127.f);
            er4[(size_t)row * 4 + hw] = vr;
          }
        }
      }
    }
  } else {
    // bf16 output, standard layout
    float pel[4][4] = {{0.f}}, per_[4][4] = {{0.f}};
#pragma unroll
    for (int m = 0; m < 4; ++m) {
#pragma unroll
      for (int n = 0; n < NF; ++n) {
        const int col = col0 + wn * (NF * 16) + n * 16 + l15;
#pragma unroll
        for (int j = 0; j < 4; ++j) {
          const int row = row0 + wm * 64 + m * 16 + lg * 4 + j;
          const float v = acc[m][n][j];
          if (row < M) Chi[(size_t)row * Ncols + col] = f2bf(v);
          pel[m][j] = fmaf(v, alw[n], pel[m][j]);
          per_[m][j] = fmaf(v, arw[n], per_[m][j]);
        }
      }
    }
    float rl[4][4], rr[4][4];
#pragma unroll
    for (int m = 0; m < 4; ++m) {
#pragma unroll
      for (int j = 0; j < 4; ++j) {
        float vl = pel[m][j], vr = per_[m][j];
#pragma unroll
        for (int off = 1; off < 16; off <<= 1) {
          vl += __shfl_xor(vl, off);
          vr += __shfl_xor(vr, off);
        }
        rl[m][j] = vl; rr[m][j] = vr;
      }
    }
    __shared__ float sl[128], sr[128];
    if (wn == 1 && l15 == 0) {
#pragma unroll
      for (int m = 0; m < 4; ++m)
#pragma unroll
        for (int j = 0; j < 4; ++j) {
          const int lr = wm * 64 + m * 16 + lg * 4 + j;
          sl[lr] = rl[m][j]; sr[lr] = rr[m][j];
        }
    }
    __syncthreads();
    if (wn == 0 && l15 == 0) {
#pragma unroll
      for (int m = 0; m < 4; ++m)
#pragma unroll
        for (int j = 0; j < 4; ++j) {
          const int lr = wm * 64 + m * 16 + lg * 4 + j;
          const int row = row0 + lr;
          if (row < M) {
            el1[row] = rl[m][j] + sl[lr];
            er1[row] = rr[m][j] + sr[lr];
          }
        }
    }
  }
}

// ---------------- CSR build ----------------
__global__ void hist_kernel(const int* __restrict__ dst, int* __restrict__ deg, int E) {
  int i = blockIdx.x * blockDim.x + threadIdx.x;
  if (i < E) atomicAdd(&deg[dst[i]], 1);
}

__global__ void scan1(const int* __restrict__ deg, int* __restrict__ offs,
                      int* __restrict__ bsums, int N) {
  __shared__ int tmp[256];
  const int tid = threadIdx.x;
  const int i = blockIdx.x * 256 + tid;
  int v = (i < N) ? deg[i] : 0;
  tmp[tid] = v;
  __syncthreads();
  for (int d = 1; d < 256; d <<= 1) {
    int t = (tid >= d) ? tmp[tid - d] : 0;
    __syncthreads();
    tmp[tid] += t;
    __syncthreads();
  }
  if (i < N) offs[i] = tmp[tid] - v;
  if (tid == 255) bsums[blockIdx.x] = tmp[255];
}

__global__ void scan2(int* __restrict__ bsums, int nb) {
  __shared__ int tmp[256];
  const int tid = threadIdx.x;
  int v = (tid < nb) ? bsums[tid] : 0;
  tmp[tid] = v;
  __syncthreads();
  for (int d = 1; d < 256; d <<= 1) {
    int t = (tid >= d) ? tmp[tid - d] : 0;
    __syncthreads();
    tmp[tid] += t;
    __syncthreads();
  }
  if (tid < nb) bsums[tid] = tmp[tid] - v;
}

__global__ void scan3(int* __restrict__ offs, const int* __restrict__ bsums,
                      int* __restrict__ cursor, int N, int E) {
  const int i = blockIdx.x * 256 + threadIdx.x;
  if (i < N) {
    const int v = offs[i] + bsums[blockIdx.x];
    offs[i] = v;
    cursor[i] = v;
  }
  if (i == 0) offs[N] = E;
}

__global__ void scatter_kernel(const int* __restrict__ src, const int* __restrict__ dst,
                               int* __restrict__ cursor, int* __restrict__ csr_src, int E) {
  int i = blockIdx.x * blockDim.x + threadIdx.x;
  if (i >= E) return;
  int pos = atomicAdd(&cursor[dst[i]], 1);
  csr_src[pos] = src[i];
}

// ---------------- alpha H=4: 16-lane group per dst node; alpha' = alpha * scale[src] ----------------
__global__ void alpha16_h4(const int* __restrict__ offs, const int* __restrict__ csr_src,
                           const float* __restrict__ elsc, const float* __restrict__ er4,
                           unsigned short* __restrict__ abuf, int N) {
  const int w = (int)((blockIdx.x * (size_t)blockDim.x + threadIdx.x) >> 6);
  const int lane = threadIdx.x & 63;
  const int g = lane >> 4, q = lane & 15;
  const int node = w * 4 + g;
  int beg = 0, end = 0;
  float erh[4] = {0.f, 0.f, 0.f, 0.f};
  if (node < N) {
    beg = offs[node]; end = offs[node + 1];
    float4 t = *reinterpret_cast<const float4*>(&er4[(size_t)node * 4]);
    erh[0] = t.x; erh[1] = t.y; erh[2] = t.z; erh[3] = t.w;
  }
  float m[4], s[4];
#pragma unroll
  for (int h = 0; h < 4; ++h) { m[h] = -INFINITY; s[h] = 0.f; }
  for (int i0 = beg; i0 < end; i0 += 16) {
    const int i = i0 + q;
    const bool valid = i < end;
    const int sn = valid ? csr_src[i] : 0;
    float4 v = *reinterpret_cast<const float4*>(&elsc[(size_t)sn * 8]);
    float e[4] = {v.x + erh[0], v.y + erh[1], v.z + erh[2], v.w + erh[3]};
#pragma unroll
    for (int h = 0; h < 4; ++h) {
      e[h] = e[h] > 0.f ? e[h] : NEG_SLOPE * e[h];
      if (!valid) e[h] = -INFINITY;
      float cm = e[h];
#pragma unroll
      for (int off = 1; off < 16; off <<= 1) cm = fmaxf(cm, __shfl_xor(cm, off));
      const float nm = fmaxf(m[h], cm);
      float cs = __expf(e[h] - nm);
#pragma unroll
      for (int off = 1; off < 16; off <<= 1) cs += __shfl_xor(cs, off);
      s[h] = s[h] * __expf(m[h] - nm) + cs;
      m[h] = nm;
    }
  }
  float inv[4];
#pragma unroll
  for (int h = 0; h < 4; ++h) inv[h] = 1.f / fmaxf(s[h], 1e-9f);
  for (int i0 = beg; i0 < end; i0 += 16) {
    const int i = i0 + q;
    if (i < end) {
      const int sn = csr_src[i];
      float4 v = *reinterpret_cast<const float4*>(&elsc[(size_t)sn * 8]);
      float4 sc = *reinterpret_cast<const float4*>(&elsc[(size_t)sn * 8 + 4]);
      float e[4] = {v.x + erh[0], v.y + erh[1], v.z + erh[2], v.w + erh[3]};
      const float scv[4] = {sc.x, sc.y, sc.z, sc.w};
#pragma unroll
      for (int h = 0; h < 4; ++h) {
        e[h] = e[h] > 0.f ? e[h] : NEG_SLOPE * e[h];
        e[h] = __expf(e[h] - m[h]) * inv[h] * scv[h];
      }
      ushort4 o;
      o.x = f2bf(e[0]); o.y = f2bf(e[1]); o.z = f2bf(e[2]); o.w = f2bf(e[3]);
      *reinterpret_cast<ushort4*>(&abuf[(size_t)i * 4]) = o;
    }
  }
}

// ---------------- alpha H=1: 16-lane group per dst node ----------------
__global__ void alpha16_h1(const int* __restrict__ offs, const int* __restrict__ csr_src,
                           const float* __restrict__ el, const float* __restrict__ er,
                           unsigned short* __restrict__ abuf, int N) {
  const int w = (int)((blockIdx.x * (size_t)blockDim.x + threadIdx.x) >> 6);
  const int lane = threadIdx.x & 63;
  const int g = lane >> 4, q = lane & 15;
  const int node = w * 4 + g;
  int beg = 0, end = 0;
  float erh = 0.f;
  if (node < N) { beg = offs[node]; end = offs[node + 1]; erh = er[node]; }
  float m = -INFINITY, s = 0.f;
  for (int i0 = beg; i0 < end; i0 += 16) {
    const int i = i0 + q;
    const bool valid = i < end;
    const int sn = valid ? csr_src[i] : 0;
    float e = el[sn] + erh;
    e = e > 0.f ? e : NEG_SLOPE * e;
    if (!valid) e = -INFINITY;
    float cm = e;
#pragma unroll
    for (int off = 1; off < 16; off <<= 1) cm = fmaxf(cm, __shfl_xor(cm, off));
    const float nm = fmaxf(m, cm);
    float cs = __expf(e - nm);
#pragma unroll
    for (int off = 1; off < 16; off <<= 1) cs += __shfl_xor(cs, off);
    s = s * __expf(m - nm) + cs;
    m = nm;
  }
  const float inv = 1.f / fmaxf(s, 1e-9f);
  for (int i0 = beg; i0 < end; i0 += 16) {
    const int i = i0 + q;
    if (i < end) {
      const int sn = csr_src[i];
      float e = el[sn] + erh;
      e = e > 0.f ? e : NEG_SLOPE * e;
      abuf[i] = f2bf(__expf(e - m) * inv);
    }
  }
}

// ---------------- aggregate H=4: one wave/node, INT8 uchar4 gather, 8-edge unroll ----------------
// qtab[node][f=lane][h=0..3] int8; abuf = alpha*scale (bf16 x4). Output bf16 interleaved.
__global__ void aggregate_h4(const int* __restrict__ offs, const int* __restrict__ csr_src,
                             const unsigned* __restrict__ qtab, const ushort4* __restrict__ abuf4,
                             const float* __restrict__ bias, ushort4* __restrict__ out4, int N) {
  const int node = (int)((blockIdx.x * (size_t)blockDim.x + threadIdx.x) >> 6);
  const int lane = threadIdx.x & 63;
  if (node >= N) return;
  const int beg = offs[node], end = offs[node + 1];
  float a0 = 0.f, a1 = 0.f, a2 = 0.f, a3 = 0.f;
  int i = beg;
  for (; i + 7 < end; i += 8) {
    int sn[8]; ushort4 w[8]; unsigned qw[8];
#pragma unroll
    for (int u = 0; u < 8; ++u) sn[u] = csr_src[i + u];
#pragma unroll
    for (int u = 0; u < 8; ++u) w[u] = abuf4[i + u];
#pragma unroll
    for (int u = 0; u < 8; ++u) qw[u] = qtab[(size_t)sn[u] * 64 + lane];
#pragma unroll
    for (int u = 0; u < 8; ++u) {
      a0 = fmaf(bf2f(w[u].x), (float)(int)(signed char)(qw[u] & 0xff), a0);
      a1 = fmaf(bf2f(w[u].y), (float)(int)(signed char)((qw[u] >> 8) & 0xff), a1);
      a2 = fmaf(bf2f(w[u].z), (float)(int)(signed char)((qw[u] >> 16) & 0xff), a2);
      a3 = fmaf(bf2f(w[u].w), (float)(int)(signed char)(qw[u] >> 24), a3);
    }
  }
  for (; i < end; ++i) {
    const int sn = csr_src[i];
    const ushort4 w = abuf4[i];
    const unsigned qw = qtab[(size_t)sn * 64 + lane];
    a0 = fmaf(bf2f(w.x), (float)(int)(signed char)(qw & 0xff), a0);
    a1 = fmaf(bf2f(w.y), (float)(int)(signed char)((qw >> 8) & 0xff), a1);
    a2 = fmaf(bf2f(w.z), (float)(int)(signed char)((qw >> 16) & 0xff), a2);
    a3 = fmaf(bf2f(w.w), (float)(int)(signed char)(qw >> 24), a3);
  }
  const float o0 = a0 + bias[lane];
  const float o1 = a1 + bias[64 + lane];
  const float o2 = a2 + bias[128 + lane];
  const float o3 = a3 + bias[192 + lane];
  ushort4 ov;
  ov.x = f2bf(o0); ov.y = f2bf(o1); ov.z = f2bf(o2); ov.w = f2bf(o3);
  out4[(size_t)node * 64 + lane] = ov;
}

// ---------------- aggregate H=1: 16-lane groups, 4 edges/iter (bf16 table) ----------------
__global__ void aggregate1(const int* __restrict__ offs, const int* __restrict__ csr_src,
                           const unsigned short* __restrict__ featH, const unsigned short* __restrict__ abuf,
                           const float* __restrict__ bias, float* __restrict__ outf, int N) {
  const int wid = (int)((blockIdx.x * (size_t)blockDim.x + threadIdx.x) >> 6);
  const int lane = threadIdx.x & 63;
  if (wid >= N) return;
  const int beg = offs[wid], end = offs[wid + 1];
  const int g = lane >> 4, q = lane & 15;
  float4 acc = make_float4(0.f, 0.f, 0.f, 0.f);
  for (int i0 = beg; i0 < end; i0 += 4) {
    const int e = i0 + g;
    if (e < end) {
      const int sn = csr_src[e];
      const float a = bf2f(abuf[e]);
      const ushort4 u = *reinterpret_cast<const ushort4*>(&featH[(size_t)sn * 64 + q * 4]);
      acc.x = fmaf(a, bf2f(u.x), acc.x);
      acc.y = fmaf(a, bf2f(u.y), acc.y);
      acc.z = fmaf(a, bf2f(u.z), acc.z);
      acc.w = fmaf(a, bf2f(u.w), acc.w);
    }
  }
#pragma unroll
  for (int off = 16; off <= 32; off <<= 1) {
    acc.x += __shfl_xor(acc.x, off);
    acc.y += __shfl_xor(acc.y, off);
    acc.z += __shfl_xor(acc.z, off);
    acc.w += __shfl_xor(acc.w, off);
  }
  if (lane < 16) {
    const float4 b4 = *reinterpret_cast<const float4*>(&bias[q * 4]);
    float4 o = make_float4(acc.x + b4.x, acc.y + b4.y, acc.z + b4.z, acc.w + b4.w);
    *reinterpret_cast<float4*>(&outf[(size_t)wid * 64 + q * 4]) = o;
  }
}

// ---------------- tail: ids as float ----------------
__global__ void copy_ids(const int* __restrict__ ids, float* __restrict__ out, int n) {
  int i = blockIdx.x * blockDim.x + threadIdx.x;
  if (i < n) out[i] = (float)ids[i];
}

extern "C" void kernel_launch(void* const* d_in, const int* in_sizes, int n_in,
                              void* d_out, int out_size, void* d_ws, size_t ws_size,
                              hipStream_t stream) {
  const float* h   = (const float*)d_in[0];
  const int* src   = (const int*)d_in[1];
  const int* dst   = (const int*)d_in[2];
  const int* ids   = (const int*)d_in[3];
  const float* W0  = (const float*)d_in[4];
  const float* al0 = (const float*)d_in[5];
  const float* ar0 = (const float*)d_in[6];
  const float* b0  = (const float*)d_in[7];
  const float* W1  = (const float*)d_in[8];
  const float* al1 = (const float*)d_in[9];
  const float* ar1 = (const float*)d_in[10];
  const float* b1  = (const float*)d_in[11];
  const float* W2  = (const float*)d_in[12];
  const float* al2 = (const float*)d_in[13];
  const float* ar2 = (const float*)d_in[14];
  const float* b2  = (const float*)d_in[15];

  const int Din = 256, HF = 256, F2 = 64;
  const int N = in_sizes[0] / Din;        // 50000
  const int E = in_sizes[1];              // 800000
  const int NIDS = in_sizes[3];           // 1024

  // workspace layout (16B-aligned chunks)
  char* p = (char*)d_ws;
  signed char* Cq = (signed char*)p;   p += (size_t)N * 256;           // int8 msg table (H=4)
  unsigned short* Chi = (unsigned short*)p; p += (size_t)N * 64 * 2;   // bf16 table (layer 2)
  unsigned short* Ahi = (unsigned short*)p; p += (size_t)N * 256 * 2;  // GEMM input (bf16)
  unsigned short* W0hi = (unsigned short*)p; p += (size_t)HF * Din * 2;
  unsigned short* W1hi = (unsigned short*)p; p += (size_t)HF * HF * 2;
  unsigned short* W2hi = (unsigned short*)p; p += (size_t)F2 * HF * 2;
  float* elsc = (float*)p;             p += (size_t)N * 8 * 4;         // el[4] + scale[4]
  float* er4  = (float*)p;             p += (size_t)N * 4 * 4;
  float* el1  = (float*)p;             p += (size_t)N * 4;
  float* er1  = (float*)p;             p += (size_t)N * 4;
  unsigned short* abuf = (unsigned short*)p; p += (size_t)E * 4 * 2;   // alpha (x scale) bf16
  int* deg    = (int*)p;               p += (size_t)N * 4;             // also cursor
  int* offs   = (int*)p;               p += (size_t)(N + 16) * 4;
  int* bsums  = (int*)p;               p += 256 * 4;
  int* csr_src = (int*)p;              p += (size_t)E * 4;

  float* outp = (float*)d_out;
  dim3 blk(256);
  const int nb = cdiv(N, 256);
  const int nwAlpha = cdiv(cdiv(N, 4) * 64, 256);

  // ---------------- weight splits (one launch) ----------------
  splitT_all<<<cdiv(256 * 256 * 2 + 256 * 64, 256), blk, 0, stream>>>(
      W0, W0hi, W1, W1hi, W2, W2hi);

  // ---------------- CSR build (shared by all 3 layers) ----------------
  hipMemsetAsync(deg, 0, (size_t)N * 4, stream);
  hist_kernel<<<cdiv(E, 256), blk, 0, stream>>>(dst, deg, E);
  scan1<<<nb, blk, 0, stream>>>(deg, offs, bsums, N);
  scan2<<<1, blk, 0, stream>>>(bsums, nb);
  scan3<<<nb, blk, 0, stream>>>(offs, bsums, deg, N, E);   // deg becomes cursor
  scatter_kernel<<<cdiv(E, 256), blk, 0, stream>>>(src, dst, deg, csr_src, E);

  // ---------------- layer 0 (H=4): h(f32) -> Cq(int8) -> Ahi(interleaved bf16) ----------------
  {
    dim3 g(cdiv(N, 128), HF / 128);
    gemm_split<4, true><<<g, blk, 0, stream>>>(nullptr, h, W0hi, nullptr, Cq, al0, ar0,
                                               elsc, er4, nullptr, nullptr, N, Din, HF);
    alpha16_h4<<<nwAlpha, blk, 0, stream>>>(offs, csr_src, elsc, er4, abuf, N);
    aggregate_h4<<<cdiv(N * 64, 256), blk, 0, stream>>>(offs, csr_src, (const unsigned*)Cq,
                                                        (const ushort4*)abuf, b0, (ushort4*)Ahi, N);
  }
  // ---------------- layer 1 (H=4) ----------------
  {
    dim3 g(cdiv(N, 128), HF / 128);
    gemm_split<4, false><<<g, blk, 0, stream>>>(Ahi, nullptr, W1hi, nullptr, Cq, al1, ar1,
                                                elsc, er4, nullptr, nullptr, N, HF, HF);
    alpha16_h4<<<nwAlpha, blk, 0, stream>>>(offs, csr_src, elsc, er4, abuf, N);
    aggregate_h4<<<cdiv(N * 64, 256), blk, 0, stream>>>(offs, csr_src, (const unsigned*)Cq,
                                                        (const ushort4*)abuf, b1, (ushort4*)Ahi, N);
  }
  // ---------------- layer 2 (H=1): -> d_out (bf16 table, standard layout) ----------------
  {
    dim3 g(cdiv(N, 128), 1);
    gemm_split<2, false><<<g, blk, 0, stream>>>(Ahi, nullptr, W2hi, Chi, nullptr, al2, ar2,
                                                nullptr, nullptr, el1, er1, N, HF, F2);
    alpha16_h1<<<nwAlpha, blk, 0, stream>>>(offs, csr_src, el1, er1, abuf, N);
    aggregate1<<<cdiv(N * 64, 256), blk, 0, stream>>>(offs, csr_src, Chi, abuf, b2, outp, N);
  }
  // ---------------- tail ids ----------------
  copy_ids<<<cdiv(NIDS, 256), blk, 0, stream>>>(ids, outp + (size_t)N * F2, NIDS);
}

// Round 14
// 330.619 us; speedup vs baseline: 1.3296x; 1.0943x over previous
//
#include <hip/hip_runtime.h>
#include <hip/hip_bf16.h>

#define NEG_SLOPE 0.2f

typedef __attribute__((ext_vector_type(8))) short bf16x8;
typedef __attribute__((ext_vector_type(4))) float f32x4;

static inline int cdiv(int a, int b) { return (a + b - 1) / b; }

__device__ inline unsigned short f2bf(float x) {
  __hip_bfloat16 b = __float2bfloat16(x);
  return *reinterpret_cast<unsigned short*>(&b);
}
__device__ inline float bf2f(unsigned short u) {
  unsigned int v = (unsigned int)u << 16;
  return *reinterpret_cast<float*>(&v);
}

// ---------------- fused split+transpose (bf16 hi only) for all 3 weights ----------------
__global__ void splitT_all(const float* __restrict__ W0, unsigned short* __restrict__ W0hi,
                           const float* __restrict__ W1, unsigned short* __restrict__ W1hi,
                           const float* __restrict__ W2, unsigned short* __restrict__ W2hi) {
  const int S0 = 256 * 256, S1 = 256 * 256, S2 = 256 * 64;
  int i = blockIdx.x * blockDim.x + threadIdx.x;
  const float* W; unsigned short* hi; int K, Mo, perm;
  if (i < S0) { W = W0; hi = W0hi; K = 256; Mo = 256; perm = 0; }
  else if (i < S0 + S1) { i -= S0; W = W1; hi = W1hi; K = 256; Mo = 256; perm = 1; }
  else if (i < S0 + S1 + S2) { i -= S0 + S1; W = W2; hi = W2hi; K = 256; Mo = 64; perm = 1; }
  else return;
  int k = i / Mo, m = i - k * Mo;
  int kk = perm ? ((k & 63) * 4 + (k >> 6)) : k;
  hi[(size_t)m * K + kk] = f2bf(W[i]);
}

// ---------------- GEMM (single bf16 MFMA) + fused score partials ----------------
// BM = MF*32 rows, BN = NF*32 cols, 4 waves (2 row-groups x 2 col-groups).
// NF=4: int8 msg out (head-interleaved) + per-(row,head) scale; elsc/er4 plain store.
// NF=2: bf16 out standard layout; el1/er1 cross-wave LDS reduce + plain store.
template <int MF, int NF, bool CVT>
__global__ __launch_bounds__(256) void gemm_split(
    const unsigned short* __restrict__ Ahi, const float* __restrict__ Af32,
    const unsigned short* __restrict__ BThi,
    unsigned short* __restrict__ Chi, signed char* __restrict__ Cq,
    const float* __restrict__ alv, const float* __restrict__ arv,
    float* __restrict__ elsc, float* __restrict__ er4,
    float* __restrict__ el1, float* __restrict__ er1,
    int M, int K, int Ncols) {
  constexpr int BM = MF * 32;
  constexpr int BN = NF * 32;
  __shared__ unsigned short As[BM][40];
  __shared__ unsigned short Bs[BN][40];
  const int tid = threadIdx.x;
  const int row0 = blockIdx.x * BM;
  const int col0 = blockIdx.y * BN;
  const int wid = tid >> 6, lane = tid & 63;
  const int wm = wid >> 1, wn = wid & 1;
  const int l15 = lane & 15, lg = lane >> 4;
  f32x4 acc[MF][NF];
#pragma unroll
  for (int m = 0; m < MF; ++m)
#pragma unroll
    for (int n = 0; n < NF; ++n) acc[m][n] = (f32x4){0.f, 0.f, 0.f, 0.f};

  const uint4 zero4 = {0u, 0u, 0u, 0u};
  for (int k0 = 0; k0 < K; k0 += 32) {
    {  // stage A
      int r = tid >> 2;
      const int kg = tid & 3;
#pragma unroll
      for (int it = 0; it < BM / 64; ++it, r += 64) {
        const int grow = row0 + r;
        if constexpr (CVT) {
          float4 f0 = make_float4(0.f, 0.f, 0.f, 0.f), f1 = f0;
          if (grow < M) {
            f0 = *reinterpret_cast<const float4*>(&Af32[(size_t)grow * K + k0 + kg * 8]);
            f1 = *reinterpret_cast<const float4*>(&Af32[(size_t)grow * K + k0 + kg * 8 + 4]);
          }
          unsigned short t[8];
          t[0] = f2bf(f0.x); t[1] = f2bf(f0.y); t[2] = f2bf(f0.z); t[3] = f2bf(f0.w);
          t[4] = f2bf(f1.x); t[5] = f2bf(f1.y); t[6] = f2bf(f1.z); t[7] = f2bf(f1.w);
          *reinterpret_cast<uint4*>(&As[r][kg * 8]) = *reinterpret_cast<const uint4*>(t);
        } else {
          uint4 vh = zero4;
          if (grow < M) vh = *reinterpret_cast<const uint4*>(&Ahi[(size_t)grow * K + k0 + kg * 8]);
          *reinterpret_cast<uint4*>(&As[r][kg * 8]) = vh;
        }
      }
    }
    {  // stage B hi
      int r = tid >> 2;
      const int kg = tid & 3;
#pragma unroll
      for (int it = 0; it < BN / 64; ++it, r += 64) {
        const int gcol = col0 + r;
        uint4 vh = *reinterpret_cast<const uint4*>(&BThi[(size_t)gcol * K + k0 + kg * 8]);
        *reinterpret_cast<uint4*>(&Bs[r][kg * 8]) = vh;
      }
    }
    __syncthreads();
    bf16x8 ah[MF];
#pragma unroll
    for (int m = 0; m < MF; ++m) {
      const int row = wm * (MF * 16) + m * 16 + l15;
      ah[m] = *reinterpret_cast<const bf16x8*>(&As[row][lg * 8]);
    }
#pragma unroll
    for (int n = 0; n < NF; ++n) {
      const int col = wn * (NF * 16) + n * 16 + l15;
      bf16x8 bh = *reinterpret_cast<const bf16x8*>(&Bs[col][lg * 8]);
#pragma unroll
      for (int m = 0; m < MF; ++m)
        acc[m][n] = __builtin_amdgcn_mfma_f32_16x16x32_bf16(ah[m], bh, acc[m][n], 0, 0, 0);
    }
    __syncthreads();
  }
  const int hw = (col0 + wn * (NF * 16)) >> 6;
  float alw[NF], arw[NF];
#pragma unroll
  for (int n = 0; n < NF; ++n) {
    const int colg = col0 + wn * (NF * 16) + n * 16 + l15;
    alw[n] = alv[colg];
    arw[n] = arv[colg];
  }

  if constexpr (NF == 4) {
#pragma unroll
    for (int m = 0; m < MF; ++m) {
#pragma unroll
      for (int j = 0; j < 4; ++j) {
        float mx = 0.f, vl = 0.f, vr = 0.f;
#pragma unroll
        for (int n = 0; n < 4; ++n) {
          const float v = acc[m][n][j];
          mx = fmaxf(mx, fabsf(v));
          vl = fmaf(v, alw[n], vl);
          vr = fmaf(v, arw[n], vr);
        }
#pragma unroll
        for (int off = 1; off < 16; off <<= 1) {
          mx = fmaxf(mx, __shfl_xor(mx, off));
          vl += __shfl_xor(vl, off);
          vr += __shfl_xor(vr, off);
        }
        const int row = row0 + wm * (MF * 16) + m * 16 + lg * 4 + j;
        if (row < M) {
          const float rinv = mx > 0.f ? 127.f / mx : 0.f;
#pragma unroll
          for (int n = 0; n < 4; ++n) {
            const int f = n * 16 + l15;
            const int q = __float2int_rn(acc[m][n][j] * rinv);
            Cq[(size_t)row * 256 + (f << 2) + hw] = (signed char)q;
          }
          if (l15 == 0) {
            elsc[(size_t)row * 8 + hw] = vl;
            elsc[(size_t)row * 8 + 4 + hw] = mx * (1.f / 127.f);
            er4[(size_t)row * 4 + hw] = vr;
          }
        }
      }
    }
  } else {
    float pel[MF][4] = {{0.f}}, per_[MF][4] = {{0.f}};
#pragma unroll
    for (int m = 0; m < MF; ++m) {
#pragma unroll
      for (int n = 0; n < NF; ++n) {
        const int col = col0 + wn * (NF * 16) + n * 16 + l15;
#pragma unroll
        for (int j = 0; j < 4; ++j) {
          const int row = row0 + wm * (MF * 16) + m * 16 + lg * 4 + j;
          const float v = acc[m][n][j];
          if (row < M) Chi[(size_t)row * Ncols + col] = f2bf(v);
          pel[m][j] = fmaf(v, alw[n], pel[m][j]);
          per_[m][j] = fmaf(v, arw[n], per_[m][j]);
        }
      }
    }
    float rl[MF][4], rr[MF][4];
#pragma unroll
    for (int m = 0; m < MF; ++m) {
#pragma unroll
      for (int j = 0; j < 4; ++j) {
        float vl = pel[m][j], vr = per_[m][j];
#pragma unroll
        for (int off = 1; off < 16; off <<= 1) {
          vl += __shfl_xor(vl, off);
          vr += __shfl_xor(vr, off);
        }
        rl[m][j] = vl; rr[m][j] = vr;
      }
    }
    __shared__ float sl[BM], sr[BM];
    if (wn == 1 && l15 == 0) {
#pragma unroll
      for (int m = 0; m < MF; ++m)
#pragma unroll
        for (int j = 0; j < 4; ++j) {
          const int lr = wm * (MF * 16) + m * 16 + lg * 4 + j;
          sl[lr] = rl[m][j]; sr[lr] = rr[m][j];
        }
    }
    __syncthreads();
    if (wn == 0 && l15 == 0) {
#pragma unroll
      for (int m = 0; m < MF; ++m)
#pragma unroll
        for (int j = 0; j < 4; ++j) {
          const int lr = wm * (MF * 16) + m * 16 + lg * 4 + j;
          const int row = row0 + lr;
          if (row < M) {
            el1[row] = rl[m][j] + sl[lr];
            er1[row] = rr[m][j] + sr[lr];
          }
        }
    }
  }
}

// ---------------- CSR build: XCD-partitioned by dst stripe ----------------
// partition p = (dst>>10)&7; blocks with blockIdx&7==p handle it (round-robin
// blockIdx->XCD keeps each csr line / cursor entry XCD-local; perf-only assumption).
__global__ void hist_part(const int* __restrict__ dst, int* __restrict__ deg, int E) {
  const int part = blockIdx.x & 7;
  const int chunk = blockIdx.x >> 3;
  const int nchunk = gridDim.x >> 3;
  for (int i = chunk * 256 + threadIdx.x; i < E; i += nchunk * 256) {
    const int d = dst[i];
    if (((d >> 10) & 7) == part) atomicAdd(&deg[d], 1);
  }
}

__global__ void scan1(const int* __restrict__ deg, int* __restrict__ offs,
                      int* __restrict__ bsums, int N) {
  __shared__ int tmp[256];
  const int tid = threadIdx.x;
  const int i = blockIdx.x * 256 + tid;
  int v = (i < N) ? deg[i] : 0;
  tmp[tid] = v;
  __syncthreads();
  for (int d = 1; d < 256; d <<= 1) {
    int t = (tid >= d) ? tmp[tid - d] : 0;
    __syncthreads();
    tmp[tid] += t;
    __syncthreads();
  }
  if (i < N) offs[i] = tmp[tid] - v;
  if (tid == 255) bsums[blockIdx.x] = tmp[255];
}

__global__ void scan2(int* __restrict__ bsums, int nb) {
  __shared__ int tmp[256];
  const int tid = threadIdx.x;
  int v = (tid < nb) ? bsums[tid] : 0;
  tmp[tid] = v;
  __syncthreads();
  for (int d = 1; d < 256; d <<= 1) {
    int t = (tid >= d) ? tmp[tid - d] : 0;
    __syncthreads();
    tmp[tid] += t;
    __syncthreads();
  }
  if (tid < nb) bsums[tid] = tmp[tid] - v;
}

__global__ void scan3(int* __restrict__ offs, const int* __restrict__ bsums,
                      int* __restrict__ cursor, int N, int E) {
  const int i = blockIdx.x * 256 + threadIdx.x;
  if (i < N) {
    const int v = offs[i] + bsums[blockIdx.x];
    offs[i] = v;
    cursor[i] = v;
  }
  if (i == 0) offs[N] = E;
}

__global__ void scatter_part(const int* __restrict__ src, const int* __restrict__ dst,
                             int* __restrict__ cursor, int* __restrict__ csr_src, int E) {
  const int part = blockIdx.x & 7;
  const int chunk = blockIdx.x >> 3;
  const int nchunk = gridDim.x >> 3;
  for (int i = chunk * 256 + threadIdx.x; i < E; i += nchunk * 256) {
    const int d = dst[i];
    if (((d >> 10) & 7) == part) {
      const int pos = atomicAdd(&cursor[d], 1);
      csr_src[pos] = src[i];
    }
  }
}

// ---------------- alpha H=4: 16-lane group per dst node; alpha' = alpha * scale[src] ----------------
__global__ void alpha16_h4(const int* __restrict__ offs, const int* __restrict__ csr_src,
                           const float* __restrict__ elsc, const float* __restrict__ er4,
                           unsigned short* __restrict__ abuf, int N) {
  const int w = (int)((blockIdx.x * (size_t)blockDim.x + threadIdx.x) >> 6);
  const int lane = threadIdx.x & 63;
  const int g = lane >> 4, q = lane & 15;
  const int node = w * 4 + g;
  int beg = 0, end = 0;
  float erh[4] = {0.f, 0.f, 0.f, 0.f};
  if (node < N) {
    beg = offs[node]; end = offs[node + 1];
    float4 t = *reinterpret_cast<const float4*>(&er4[(size_t)node * 4]);
    erh[0] = t.x; erh[1] = t.y; erh[2] = t.z; erh[3] = t.w;
  }
  float m[4], s[4];
#pragma unroll
  for (int h = 0; h < 4; ++h) { m[h] = -INFINITY; s[h] = 0.f; }
  for (int i0 = beg; i0 < end; i0 += 16) {
    const int i = i0 + q;
    const bool valid = i < end;
    const int sn = valid ? csr_src[i] : 0;
    float4 v = *reinterpret_cast<const float4*>(&elsc[(size_t)sn * 8]);
    float e[4] = {v.x + erh[0], v.y + erh[1], v.z + erh[2], v.w + erh[3]};
#pragma unroll
    for (int h = 0; h < 4; ++h) {
      e[h] = e[h] > 0.f ? e[h] : NEG_SLOPE * e[h];
      if (!valid) e[h] = -INFINITY;
      float cm = e[h];
#pragma unroll
      for (int off = 1; off < 16; off <<= 1) cm = fmaxf(cm, __shfl_xor(cm, off));
      const float nm = fmaxf(m[h], cm);
      float cs = __expf(e[h] - nm);
#pragma unroll
      for (int off = 1; off < 16; off <<= 1) cs += __shfl_xor(cs, off);
      s[h] = s[h] * __expf(m[h] - nm) + cs;
      m[h] = nm;
    }
  }
  float inv[4];
#pragma unroll
  for (int h = 0; h < 4; ++h) inv[h] = 1.f / fmaxf(s[h], 1e-9f);
  for (int i0 = beg; i0 < end; i0 += 16) {
    const int i = i0 + q;
    if (i < end) {
      const int sn = csr_src[i];
      float4 v = *reinterpret_cast<const float4*>(&elsc[(size_t)sn * 8]);
      float4 sc = *reinterpret_cast<const float4*>(&elsc[(size_t)sn * 8 + 4]);
      float e[4] = {v.x + erh[0], v.y + erh[1], v.z + erh[2], v.w + erh[3]};
      const float scv[4] = {sc.x, sc.y, sc.z, sc.w};
#pragma unroll
      for (int h = 0; h < 4; ++h) {
        e[h] = e[h] > 0.f ? e[h] : NEG_SLOPE * e[h];
        e[h] = __expf(e[h] - m[h]) * inv[h] * scv[h];
      }
      ushort4 o;
      o.x = f2bf(e[0]); o.y = f2bf(e[1]); o.z = f2bf(e[2]); o.w = f2bf(e[3]);
      *reinterpret_cast<ushort4*>(&abuf[(size_t)i * 4]) = o;
    }
  }
}

// ---------------- alpha H=1 ----------------
__global__ void alpha16_h1(const int* __restrict__ offs, const int* __restrict__ csr_src,
                           const float* __restrict__ el, const float* __restrict__ er,
                           unsigned short* __restrict__ abuf, int N) {
  const int w = (int)((blockIdx.x * (size_t)blockDim.x + threadIdx.x) >> 6);
  const int lane = threadIdx.x & 63;
  const int g = lane >> 4, q = lane & 15;
  const int node = w * 4 + g;
  int beg = 0, end = 0;
  float erh = 0.f;
  if (node < N) { beg = offs[node]; end = offs[node + 1]; erh = er[node]; }
  float m = -INFINITY, s = 0.f;
  for (int i0 = beg; i0 < end; i0 += 16) {
    const int i = i0 + q;
    const bool valid = i < end;
    const int sn = valid ? csr_src[i] : 0;
    float e = el[sn] + erh;
    e = e > 0.f ? e : NEG_SLOPE * e;
    if (!valid) e = -INFINITY;
    float cm = e;
#pragma unroll
    for (int off = 1; off < 16; off <<= 1) cm = fmaxf(cm, __shfl_xor(cm, off));
    const float nm = fmaxf(m, cm);
    float cs = __expf(e - nm);
#pragma unroll
    for (int off = 1; off < 16; off <<= 1) cs += __shfl_xor(cs, off);
    s = s * __expf(m - nm) + cs;
    m = nm;
  }
  const float inv = 1.f / fmaxf(s, 1e-9f);
  for (int i0 = beg; i0 < end; i0 += 16) {
    const int i = i0 + q;
    if (i < end) {
      const int sn = csr_src[i];
      float e = el[sn] + erh;
      e = e > 0.f ? e : NEG_SLOPE * e;
      abuf[i] = f2bf(__expf(e - m) * inv);
    }
  }
}

// ---------------- aggregate H=4: one wave/node, INT8 uchar4 gather, 8-edge unroll ----------------
__global__ void aggregate_h4(const int* __restrict__ offs, const int* __restrict__ csr_src,
                             const unsigned* __restrict__ qtab, const ushort4* __restrict__ abuf4,
                             const float* __restrict__ bias, ushort4* __restrict__ out4, int N) {
  const int node = (int)((blockIdx.x * (size_t)blockDim.x + threadIdx.x) >> 6);
  const int lane = threadIdx.x & 63;
  if (node >= N) return;
  const int beg = offs[node], end = offs[node + 1];
  float a0 = 0.f, a1 = 0.f, a2 = 0.f, a3 = 0.f;
  int i = beg;
  for (; i + 7 < end; i += 8) {
    int sn[8]; ushort4 w[8]; unsigned qw[8];
#pragma unroll
    for (int u = 0; u < 8; ++u) sn[u] = csr_src[i + u];
#pragma unroll
    for (int u = 0; u < 8; ++u) w[u] = abuf4[i + u];
#pragma unroll
    for (int u = 0; u < 8; ++u) qw[u] = qtab[(size_t)sn[u] * 64 + lane];
#pragma unroll
    for (int u = 0; u < 8; ++u) {
      a0 = fmaf(bf2f(w[u].x), (float)(int)(signed char)(qw[u] & 0xff), a0);
      a1 = fmaf(bf2f(w[u].y), (float)(int)(signed char)((qw[u] >> 8) & 0xff), a1);
      a2 = fmaf(bf2f(w[u].z), (float)(int)(signed char)((qw[u] >> 16) & 0xff), a2);
      a3 = fmaf(bf2f(w[u].w), (float)(int)(signed char)(qw[u] >> 24), a3);
    }
  }
  for (; i < end; ++i) {
    const int sn = csr_src[i];
    const ushort4 w = abuf4[i];
    const unsigned qw = qtab[(size_t)sn * 64 + lane];
    a0 = fmaf(bf2f(w.x), (float)(int)(signed char)(qw & 0xff), a0);
    a1 = fmaf(bf2f(w.y), (float)(int)(signed char)((qw >> 8) & 0xff), a1);
    a2 = fmaf(bf2f(w.z), (float)(int)(signed char)((qw >> 16) & 0xff), a2);
    a3 = fmaf(bf2f(w.w), (float)(int)(signed char)(qw >> 24), a3);
  }
  const float o0 = a0 + bias[lane];
  const float o1 = a1 + bias[64 + lane];
  const float o2 = a2 + bias[128 + lane];
  const float o3 = a3 + bias[192 + lane];
  ushort4 ov;
  ov.x = f2bf(o0); ov.y = f2bf(o1); ov.z = f2bf(o2); ov.w = f2bf(o3);
  out4[(size_t)node * 64 + lane] = ov;
}

// ---------------- aggregate H=1: 16-lane groups, 4 edges/iter (bf16 table) ----------------
__global__ void aggregate1(const int* __restrict__ offs, const int* __restrict__ csr_src,
                           const unsigned short* __restrict__ featH, const unsigned short* __restrict__ abuf,
                           const float* __restrict__ bias, float* __restrict__ outf, int N) {
  const int wid = (int)((blockIdx.x * (size_t)blockDim.x + threadIdx.x) >> 6);
  const int lane = threadIdx.x & 63;
  if (wid >= N) return;
  const int beg = offs[wid], end = offs[wid + 1];
  const int g = lane >> 4, q = lane & 15;
  float4 acc = make_float4(0.f, 0.f, 0.f, 0.f);
  for (int i0 = beg; i0 < end; i0 += 4) {
    const int e = i0 + g;
    if (e < end) {
      const int sn = csr_src[e];
      const float a = bf2f(abuf[e]);
      const ushort4 u = *reinterpret_cast<const ushort4*>(&featH[(size_t)sn * 64 + q * 4]);
      acc.x = fmaf(a, bf2f(u.x), acc.x);
      acc.y = fmaf(a, bf2f(u.y), acc.y);
      acc.z = fmaf(a, bf2f(u.z), acc.z);
      acc.w = fmaf(a, bf2f(u.w), acc.w);
    }
  }
#pragma unroll
  for (int off = 16; off <= 32; off <<= 1) {
    acc.x += __shfl_xor(acc.x, off);
    acc.y += __shfl_xor(acc.y, off);
    acc.z += __shfl_xor(acc.z, off);
    acc.w += __shfl_xor(acc.w, off);
  }
  if (lane < 16) {
    const float4 b4 = *reinterpret_cast<const float4*>(&bias[q * 4]);
    float4 o = make_float4(acc.x + b4.x, acc.y + b4.y, acc.z + b4.z, acc.w + b4.w);
    *reinterpret_cast<float4*>(&outf[(size_t)wid * 64 + q * 4]) = o;
  }
}

// ---------------- tail: ids as float ----------------
__global__ void copy_ids(const int* __restrict__ ids, float* __restrict__ out, int n) {
  int i = blockIdx.x * blockDim.x + threadIdx.x;
  if (i < n) out[i] = (float)ids[i];
}

extern "C" void kernel_launch(void* const* d_in, const int* in_sizes, int n_in,
                              void* d_out, int out_size, void* d_ws, size_t ws_size,
                              hipStream_t stream) {
  const float* h   = (const float*)d_in[0];
  const int* src   = (const int*)d_in[1];
  const int* dst   = (const int*)d_in[2];
  const int* ids   = (const int*)d_in[3];
  const float* W0  = (const float*)d_in[4];
  const float* al0 = (const float*)d_in[5];
  const float* ar0 = (const float*)d_in[6];
  const float* b0  = (const float*)d_in[7];
  const float* W1  = (const float*)d_in[8];
  const float* al1 = (const float*)d_in[9];
  const float* ar1 = (const float*)d_in[10];
  const float* b1  = (const float*)d_in[11];
  const float* W2  = (const float*)d_in[12];
  const float* al2 = (const float*)d_in[13];
  const float* ar2 = (const float*)d_in[14];
  const float* b2  = (const float*)d_in[15];

  const int Din = 256, HF = 256, F2 = 64;
  const int N = in_sizes[0] / Din;        // 50000
  const int E = in_sizes[1];              // 800000
  const int NIDS = in_sizes[3];           // 1024

  // workspace layout (16B-aligned chunks)
  char* p = (char*)d_ws;
  signed char* Cq = (signed char*)p;   p += (size_t)N * 256;           // int8 msg table (H=4)
  unsigned short* Chi = (unsigned short*)p; p += (size_t)N * 64 * 2;   // bf16 table (layer 2)
  unsigned short* Ahi = (unsigned short*)p; p += (size_t)N * 256 * 2;  // GEMM input (bf16)
  unsigned short* W0hi = (unsigned short*)p; p += (size_t)HF * Din * 2;
  unsigned short* W1hi = (unsigned short*)p; p += (size_t)HF * HF * 2;
  unsigned short* W2hi = (unsigned short*)p; p += (size_t)F2 * HF * 2;
  float* elsc = (float*)p;             p += (size_t)N * 8 * 4;         // el[4] + scale[4]
  float* er4  = (float*)p;             p += (size_t)N * 4 * 4;
  float* el1  = (float*)p;             p += (size_t)N * 4;
  float* er1  = (float*)p;             p += (size_t)N * 4;
  unsigned short* abuf = (unsigned short*)p; p += (size_t)E * 4 * 2;   // alpha (x scale) bf16
  int* deg    = (int*)p;               p += (size_t)N * 4;             // also cursor
  int* offs   = (int*)p;               p += (size_t)(N + 16) * 4;
  int* bsums  = (int*)p;               p += 256 * 4;
  int* csr_src = (int*)p;              p += (size_t)E * 4;

  float* outp = (float*)d_out;
  dim3 blk(256);
  const int nb = cdiv(N, 256);
  const int nwAlpha = cdiv(cdiv(N, 4) * 64, 256);
  const int nbPart = 8 * 96;             // 8 partitions x 96 chunk-blocks

  // ---------------- weight splits (one launch) ----------------
  splitT_all<<<cdiv(256 * 256 * 2 + 256 * 64, 256), blk, 0, stream>>>(
      W0, W0hi, W1, W1hi, W2, W2hi);

  // ---------------- CSR build, XCD-partitioned (shared by all 3 layers) ----------------
  hipMemsetAsync(deg, 0, (size_t)N * 4, stream);
  hist_part<<<nbPart, blk, 0, stream>>>(dst, deg, E);
  scan1<<<nb, blk, 0, stream>>>(deg, offs, bsums, N);
  scan2<<<1, blk, 0, stream>>>(bsums, nb);
  scan3<<<nb, blk, 0, stream>>>(offs, bsums, deg, N, E);   // deg becomes cursor
  scatter_part<<<nbPart, blk, 0, stream>>>(src, dst, deg, csr_src, E);

  // ---------------- layer 0 (H=4): h(f32) -> Cq(int8) -> Ahi(interleaved bf16) ----------------
  {
    dim3 g(cdiv(N, 64), HF / 128);
    gemm_split<2, 4, true><<<g, blk, 0, stream>>>(nullptr, h, W0hi, nullptr, Cq, al0, ar0,
                                                  elsc, er4, nullptr, nullptr, N, Din, HF);
    alpha16_h4<<<nwAlpha, blk, 0, stream>>>(offs, csr_src, elsc, er4, abuf, N);
    aggregate_h4<<<cdiv(N * 64, 256), blk, 0, stream>>>(offs, csr_src, (const unsigned*)Cq,
                                                        (const ushort4*)abuf, b0, (ushort4*)Ahi, N);
  }
  // ---------------- layer 1 (H=4) ----------------
  {
    dim3 g(cdiv(N, 64), HF / 128);
    gemm_split<2, 4, false><<<g, blk, 0, stream>>>(Ahi, nullptr, W1hi, nullptr, Cq, al1, ar1,
                                                   elsc, er4, nullptr, nullptr, N, HF, HF);
    alpha16_h4<<<nwAlpha, blk, 0, stream>>>(offs, csr_src, elsc, er4, abuf, N);
    aggregate_h4<<<cdiv(N * 64, 256), blk, 0, stream>>>(offs, csr_src, (const unsigned*)Cq,
                                                        (const ushort4*)abuf, b1, (ushort4*)Ahi, N);
  }
  // ---------------- layer 2 (H=1): -> d_out (bf16 table, standard layout) ----------------
  {
    dim3 g(cdiv(N, 64), 1);
    gemm_split<2, 2, false><<<g, blk, 0, stream>>>(Ahi, nullptr, W2hi, Chi, nullptr, al2, ar2,
                                                   nullptr, nullptr, el1, er1, N, HF, F2);
    alpha16_h1<<<nwAlpha, blk, 0, stream>>>(offs, csr_src, el1, er1, abuf, N);
    aggregate1<<<cdiv(N * 64, 256), blk, 0, stream>>>(offs, csr_src, Chi, abuf, b2, outp, N);
  }
  // ---------------- tail ids ----------------
  copy_ids<<<cdiv(NIDS, 256), blk, 0, stream>>>(ids, outp + (size_t)N * F2, NIDS);
}